// Round 6
// baseline (2289.077 us; speedup 1.0000x reference)
//
#include <hip/hip_runtime.h>
#include <hip/hip_bf16.h>
#include <math.h>

#define BB 8
#define SS 512
#define DD 1024
#define LL 6
#define HH 8
#define HDD 128
#define FFF 4096
#define EPSF 1e-5f
#define SCALEF 0.08838834764831845f  // 1/sqrt(128)

typedef __attribute__((ext_vector_type(8))) _Float16 f16x8;
typedef __attribute__((ext_vector_type(4))) _Float16 f16x4;
typedef __attribute__((ext_vector_type(4))) float f32x4;

__device__ __forceinline__ void gload16(const void* g, void* l) {
  __builtin_amdgcn_global_load_lds(
      (const __attribute__((address_space(1))) void*)g,
      (__attribute__((address_space(3))) void*)l, 16, 0, 0);
}

// ===========================================================================
// gemm4: 256x256 tile, 512 threads (8 waves, 2M x 4N), wave-tile 128x64,
// BK=32, 8-phase-style fine interleave (2 phases per K-tile):
//  ph1: {ds_read A mi0-3 + B ni0-3 (8 b128) | stage A(t+2) (2 gload_lds) |
//        bar | lgkmcnt(0) | setprio(1) 16 MFMA setprio(0) | bar}
//  ph2: {ds_read A mi4-7 (4 b128) | stage B(t+2) | bar | lgkmcnt(0) |
//        setprio(1) 16 MFMA setprio(0) | vmcnt(4) | bar}
// 4-slot LDS ring (4 x 32KB = 128KB). vmcnt(4) at each tile boundary retires
// tile t+1's 4 staging loads; never drained to 0 in-loop (T4).
// Swizzle: 16B slot ^= (R&3)<<4, applied to global source and ds_read.
// A [M,K] rows stride Kstr; B [N,K] rows stride Kstr; K-loop = Kdim.
// emode: 1 fused-qkv scatter | 2 scores(scale+mask) | 5 gelu+bias f16 |
//        6 f16 split-K partial
// ===========================================================================
#define LDA4(SC, LO)                                                        \
  {                                                                         \
    _Pragma("unroll") for (int mi = 0; mi < 4; ++mi) {                      \
      const int R = wm + ((LO) + mi) * 16 + r16;                            \
      af[(LO) + mi] =                                                       \
          *(const f16x8*)((SC) + R * 64 + (kq16 ^ ((R & 3) << 4)));         \
    }                                                                       \
  }
#define LDB4(SC)                                                            \
  {                                                                         \
    _Pragma("unroll") for (int ni = 0; ni < 4; ++ni) {                      \
      const int R = wn + ni * 16 + r16;                                     \
      bf[ni] =                                                              \
          *(const f16x8*)((SC) + 16384 + R * 64 + (kq16 ^ ((R & 3) << 4))); \
    }                                                                       \
  }
#define MM16(LO)                                                            \
  {                                                                         \
    _Pragma("unroll") for (int mi = 0; mi < 4; ++mi)                        \
        _Pragma("unroll") for (int ni = 0; ni < 4; ++ni)                    \
            acc[(LO) + mi][ni] = __builtin_amdgcn_mfma_f32_16x16x32_f16(    \
                af[(LO) + mi], bf[ni], acc[(LO) + mi][ni], 0, 0, 0);        \
  }
#define STAGEA(DST, K0)                                                     \
  {                                                                         \
    gload16((const char*)Az + (long)sr0 * K2 + (long)(K0)*2 + scs,          \
            (DST) + so0);                                                   \
    gload16((const char*)Az + (long)(sr0 + 128) * K2 + (long)(K0)*2 + scs,  \
            (DST) + so0 + 8192);                                            \
  }
#define STAGEB(DST, K0)                                                     \
  {                                                                         \
    gload16((const char*)Bz + (long)sr0 * K2 + (long)(K0)*2 + scs,          \
            (DST) + 16384 + so0);                                           \
    gload16((const char*)Bz + (long)(sr0 + 128) * K2 + (long)(K0)*2 + scs,  \
            (DST) + 16384 + so0 + 8192);                                    \
  }
#define LGKM0                                                \
  asm volatile("s_waitcnt lgkmcnt(0)" ::: "memory");         \
  __builtin_amdgcn_sched_barrier(0);
#define KTILE(SC, DOSTA, DOSTB, TRAIL)                       \
  LDA4(SC, 0) LDB4(SC)                                       \
  DOSTA                                                      \
  __builtin_amdgcn_s_barrier();                              \
  LGKM0                                                      \
  __builtin_amdgcn_s_setprio(1);                             \
  MM16(0)                                                    \
  __builtin_amdgcn_s_setprio(0);                             \
  __builtin_amdgcn_s_barrier();                              \
  LDA4(SC, 4)                                                \
  DOSTB                                                      \
  __builtin_amdgcn_s_barrier();                              \
  LGKM0                                                      \
  __builtin_amdgcn_s_setprio(1);                             \
  MM16(4)                                                    \
  __builtin_amdgcn_s_setprio(0);                             \
  TRAIL                                                      \
  __builtin_amdgcn_s_barrier();

__global__ __launch_bounds__(512, 2) void gemm4_kernel(
    const _Float16* __restrict__ Ag, const _Float16* __restrict__ Bg,
    const float* __restrict__ bias, void* __restrict__ outp,
    const int* __restrict__ amask, int Mdim, int Ndim, int Kdim, int Kstr,
    long zsA, long zsB, long zsOut, int emode) {
  __shared__ char lb[4 * 32768];  // 128KB: 4-slot ring
  const int tid = threadIdx.x;
  const int lane = tid & 63;
  const int wid = tid >> 6;
  const int z = blockIdx.z;
  const int m0 = blockIdx.y * 256;
  const int n0 = blockIdx.x * 256;
  const long K2 = (long)Kstr * 2;  // row stride bytes
  const _Float16* Az = Ag + (long)z * zsA + (long)m0 * Kstr;
  const _Float16* Bz = Bg + (long)z * zsB + (long)n0 * Kstr;

  const int wm = (wid >> 2) * 128;  // wave-tile 128x64
  const int wn = (wid & 3) * 64;
  const int r16 = lane & 15;
  const int kq16 = (lane >> 4) * 16;  // 16B k-slot per lane group

  // staging geometry: thread stages rows sr0 and sr0+128, 16B at col scs
  const int sr0 = tid >> 2;
  const int scs = ((tid & 3) << 4) ^ ((sr0 & 3) << 4);
  const int so0 = tid * 16;  // linear LDS byte offset (lane*16 within wave)

  f32x4 acc[8][4];
#pragma unroll
  for (int mi = 0; mi < 8; ++mi)
#pragma unroll
    for (int ni = 0; ni < 4; ++ni) acc[mi][ni] = (f32x4){0.f, 0.f, 0.f, 0.f};
  f16x8 af[8], bf[4];

  const int nt = Kdim >> 5;
  // prologue: stage tiles 0 and 1; wait tile 0 (oldest 4 loads)
  STAGEA(lb, 0)
  STAGEB(lb, 0)
  STAGEA(lb + 32768, 32)
  STAGEB(lb + 32768, 32)
  asm volatile("s_waitcnt vmcnt(4)" ::: "memory");
  __builtin_amdgcn_s_barrier();

  int t = 0;
  for (; t < nt - 2; ++t) {
    char* sC = lb + ((t & 3) << 15);
    char* sP = lb + (((t + 2) & 3) << 15);
    const int k2 = (t + 2) << 5;
    KTILE(sC, STAGEA(sP, k2), STAGEB(sP, k2),
          asm volatile("s_waitcnt vmcnt(4)" ::: "memory");)
  }
  {
    char* sC = lb + ((t & 3) << 15);
    KTILE(sC, , , asm volatile("s_waitcnt vmcnt(0)" ::: "memory");)
  }
  ++t;
  {
    char* sC = lb + ((t & 3) << 15);
    KTILE(sC, , , )
  }

  _Float16* outH = (_Float16*)outp + (long)z * zsOut;
  const int rj = (lane >> 4) << 2;
  const long MSZq = (long)BB * SS * DD;
#pragma unroll
  for (int mi = 0; mi < 8; ++mi) {
#pragma unroll
    for (int ni = 0; ni < 4; ++ni) {
      const int col = n0 + wn + ni * 16 + r16;
#pragma unroll
      for (int j = 0; j < 4; ++j) {
        const int row = m0 + wm + mi * 16 + rj + j;
        float vv = acc[mi][ni][j];
        if (emode == 1) {  // fused qkv scatter; V written transposed
          vv += bias[col];
          int wsel = col >> 10, c = col & 1023;
          int b_ = row >> 9, s_ = row & 511;
          int hh = c >> 7, hd_ = c & 127;
          if (wsel < 2) {
            outH[wsel * MSZq + (((long)(b_ * HH + hh)) * SS + s_) * HDD + hd_] =
                (_Float16)vv;
          } else {  // V -> [B*H][HD][S]
            outH[2 * MSZq + (((long)(b_ * HH + hh)) * HDD + hd_) * SS + s_] =
                (_Float16)vv;
          }
        } else if (emode == 2) {  // scores: scale + key-pad mask
          int b_ = z >> 3;
          vv = (amask[b_ * SS + col] == 0) ? -10000.0f : vv * SCALEF;
          outH[(long)row * Ndim + col] = (_Float16)vv;
        } else if (emode == 5) {  // exact GELU(bias+acc), f16
          vv += bias[col];
          vv = 0.5f * vv * (1.0f + erff(vv * 0.70710678118654752f));
          outH[(long)row * Ndim + col] = (_Float16)vv;
        } else {  // 6: f16 split-K partial, no bias
          outH[(long)row * Ndim + col] = (_Float16)vv;
        }
      }
    }
  }
}

// out[row][c] = (res? res : 0) + bias + sum of 4 f16 partials   (N=1024)
__global__ __launch_bounds__(256) void reduce4_kernel(
    const _Float16* __restrict__ parts, const float* __restrict__ res,
    const float* __restrict__ bias, float* __restrict__ out, long zs) {
  const int row = blockIdx.x;
  const int c = threadIdx.x << 2;
  const long base = (long)row * DD + c;
  float4 a;
  a.x = bias[c];
  a.y = bias[c + 1];
  a.z = bias[c + 2];
  a.w = bias[c + 3];
  if (res) {
    const float4 r = *reinterpret_cast<const float4*>(&res[base]);
    a.x += r.x;
    a.y += r.y;
    a.z += r.z;
    a.w += r.w;
  }
#pragma unroll
  for (int p = 0; p < 4; ++p) {
    const f16x4 h = *reinterpret_cast<const f16x4*>(&parts[p * zs + base]);
    a.x += (float)h[0];
    a.y += (float)h[1];
    a.z += (float)h[2];
    a.w += (float)h[3];
  }
  *reinterpret_cast<float4*>(&out[base]) = a;
}

// ===========================================================================
// 128x64 kernel (PV only: N=128)
// ===========================================================================
#define TSZ 24576

#define STAGE(P, K0)                                                        \
  {                                                                         \
    _Pragma("unroll") for (int i = 0; i < 4; ++i)                           \
        gload16((const char*)(Az + (long)sra[i] * Kdim + (K0)) + sca[i],    \
                (P) + i * 4096 + wid * 1024);                               \
    _Pragma("unroll") for (int i = 0; i < 2; ++i)                           \
        gload16((const char*)(Bz + (long)srb[i] * Kdim + (K0)) + scb[i],    \
                (P) + 16384 + i * 4096 + wid * 1024);                       \
  }

#define COMPUTE(P)                                                          \
  {                                                                         \
    _Pragma("unroll") for (int kk = 0; kk < 2; ++kk) {                      \
      f16x8 af[4], bf[2];                                                   \
      _Pragma("unroll") for (int mi = 0; mi < 4; ++mi) {                    \
        const int R = wm + mi * 16 + r16;                                   \
        af[mi] = *(const f16x8*)((P) + R * 128 +                            \
                                 ((kk * 64 + kqb) ^ ((R & 7) << 4)));       \
      }                                                                     \
      _Pragma("unroll") for (int ni = 0; ni < 2; ++ni) {                    \
        const int R = wn + ni * 16 + r16;                                   \
        bf[ni] = *(const f16x8*)((P) + 16384 + R * 128 +                    \
                                 ((kk * 64 + kqb) ^ ((R & 7) << 4)));       \
      }                                                                     \
      _Pragma("unroll") for (int mi = 0; mi < 4; ++mi)                      \
          _Pragma("unroll") for (int ni = 0; ni < 2; ++ni)                  \
              acc[mi][ni] = __builtin_amdgcn_mfma_f32_16x16x32_f16(         \
                  af[mi], bf[ni], acc[mi][ni], 0, 0, 0);                    \
    }                                                                       \
  }

#define WAITBAR6                                      \
  {                                                   \
    asm volatile("s_waitcnt vmcnt(6)" ::: "memory");  \
    __builtin_amdgcn_s_barrier();                     \
  }
#define WAITBAR0                                      \
  {                                                   \
    asm volatile("s_waitcnt vmcnt(0)" ::: "memory");  \
    __builtin_amdgcn_s_barrier();                     \
  }

__global__ __launch_bounds__(256) void gemm2_kernel(
    const _Float16* __restrict__ Ag, const _Float16* __restrict__ Bg,
    void* __restrict__ outp, int Mdim, int Ndim, int Kdim, long zsA, long zsB,
    long zsOut) {
  __shared__ char lds[3 * TSZ];
  const int tid = threadIdx.x;
  const int lane = tid & 63;
  const int wid = tid >> 6;
  const int z = blockIdx.z;
  const int m0 = blockIdx.y * 128;
  const int n0 = blockIdx.x * 64;
  const _Float16* Az = Ag + (long)z * zsA + (long)m0 * Kdim;
  const _Float16* Bz = Bg + (long)z * zsB + (long)n0 * Kdim;

  const int wm = (wid >> 1) * 64;
  const int wn = (wid & 1) * 32;
  const int r16 = lane & 15;
  const int kqb = (lane >> 4) * 16;

  f32x4 acc[4][2];
#pragma unroll
  for (int mi = 0; mi < 4; ++mi)
#pragma unroll
    for (int ni = 0; ni < 2; ++ni) acc[mi][ni] = (f32x4){0.f, 0.f, 0.f, 0.f};

  int sra[4], srb[2], sca[4], scb[2];
  {
    const int cbl = (tid * 16) & 127;
#pragma unroll
    for (int i = 0; i < 4; ++i) {
      int r = i * 32 + (tid >> 3);
      sra[i] = r;
      sca[i] = cbl ^ ((r & 7) << 4);
    }
#pragma unroll
    for (int i = 0; i < 2; ++i) {
      int r = i * 32 + (tid >> 3);
      srb[i] = r;
      scb[i] = cbl ^ ((r & 7) << 4);
    }
  }

  const int nt = Kdim >> 6;
  char* p0 = lds;
  char* p1 = lds + TSZ;
  char* p2 = lds + 2 * TSZ;
  STAGE(p0, 0)
  STAGE(p1, 64)
  int t = 0;
  for (; t + 2 < nt; ++t) {
    WAITBAR6
    STAGE(p2, (t + 2) << 6)
    COMPUTE(p0)
    char* tmp = p0;
    p0 = p1;
    p1 = p2;
    p2 = tmp;
  }
  WAITBAR6
  COMPUTE(p0)
  WAITBAR0
  COMPUTE(p1)

  _Float16* outH = (_Float16*)outp;
  const int rj = (lane >> 4) << 2;
#pragma unroll
  for (int mi = 0; mi < 4; ++mi) {
#pragma unroll
    for (int ni = 0; ni < 2; ++ni) {
      const int col = n0 + wn + ni * 16 + r16;
#pragma unroll
      for (int j = 0; j < 4; ++j) {
        const int row = m0 + wm + mi * 16 + rj + j;
        const int b_ = z >> 3, hh = z & 7;
        outH[((long)(b_ * SS + row)) * DD + hh * HDD + col] =
            (_Float16)acc[mi][ni][j];
      }
    }
  }
}

// ---------------------------------------------------------------------------
__global__ __launch_bounds__(256) void embed_kernel(
    const int* __restrict__ ids, const int* __restrict__ curpos,
    const float* __restrict__ tok, const float* __restrict__ pos,
    float* __restrict__ h) {
  const int rs = blockIdx.x;
  const int s_ = rs & (SS - 1);
  const int t = ids[rs];
  const int p = curpos[0] + s_;
  const int c = threadIdx.x << 2;
  const float4 tv = *reinterpret_cast<const float4*>(&tok[(long)t * DD + c]);
  const float4 pv = *reinterpret_cast<const float4*>(&pos[(long)p * DD + c]);
  float4 o = {tv.x + pv.x, tv.y + pv.y, tv.z + pv.z, tv.w + pv.w};
  *reinterpret_cast<float4*>(&h[(long)rs * DD + c]) = o;
}

// LN: f32 in -> f16 out
__global__ __launch_bounds__(256) void ln_kernel(const float* __restrict__ in,
                                                 const float* __restrict__ g,
                                                 const float* __restrict__ bb,
                                                 _Float16* __restrict__ out) {
  const int row = blockIdx.x;
  const int c = threadIdx.x << 2;
  const float4 xv = *reinterpret_cast<const float4*>(&in[(long)row * DD + c]);
  float s = xv.x + xv.y + xv.z + xv.w;
  float ss = xv.x * xv.x + xv.y * xv.y + xv.z * xv.z + xv.w * xv.w;
#pragma unroll
  for (int off = 32; off; off >>= 1) {
    s += __shfl_down(s, off);
    ss += __shfl_down(ss, off);
  }
  __shared__ float red[8];
  const int wid = threadIdx.x >> 6, lane = threadIdx.x & 63;
  if (lane == 0) {
    red[wid] = s;
    red[4 + wid] = ss;
  }
  __syncthreads();
  if (threadIdx.x == 0) {
    s = red[0] + red[1] + red[2] + red[3];
    ss = red[4] + red[5] + red[6] + red[7];
    float mean = s * (1.0f / DD);
    float var = ss * (1.0f / DD) - mean * mean;
    red[0] = mean;
    red[1] = rsqrtf(var + EPSF);
  }
  __syncthreads();
  const float mean = red[0], rstd = red[1];
  const float4 gv = *reinterpret_cast<const float4*>(&g[c]);
  const float4 bv = *reinterpret_cast<const float4*>(&bb[c]);
  f16x4 o;
  o[0] = (_Float16)((xv.x - mean) * rstd * gv.x + bv.x);
  o[1] = (_Float16)((xv.y - mean) * rstd * gv.y + bv.y);
  o[2] = (_Float16)((xv.z - mean) * rstd * gv.z + bv.z);
  o[3] = (_Float16)((xv.w - mean) * rstd * gv.w + bv.w);
  *reinterpret_cast<f16x4*>(&out[(long)row * DD + c]) = o;
}

// wave-per-row softmax over 512 f16 cols, in place
__global__ __launch_bounds__(256) void softmax_kernel(_Float16* __restrict__ p) {
  const long row = (long)blockIdx.x * 4 + (threadIdx.x >> 6);
  const int lane = threadIdx.x & 63;
  _Float16* pr = p + row * SS;
  f16x8 hv = *reinterpret_cast<const f16x8*>(&pr[lane * 8]);
  float v[8];
#pragma unroll
  for (int j = 0; j < 8; ++j) v[j] = (float)hv[j];
  float m = v[0];
#pragma unroll
  for (int j = 1; j < 8; ++j) m = fmaxf(m, v[j]);
#pragma unroll
  for (int off = 1; off < 64; off <<= 1) m = fmaxf(m, __shfl_xor(m, off));
  float sum = 0.f;
#pragma unroll
  for (int j = 0; j < 8; ++j) {
    v[j] = expf(v[j] - m);
    sum += v[j];
  }
#pragma unroll
  for (int off = 1; off < 64; off <<= 1) sum += __shfl_xor(sum, off);
  const float inv = 1.0f / sum;
#pragma unroll
  for (int j = 0; j < 8; ++j) hv[j] = (_Float16)(v[j] * inv);
  *reinterpret_cast<f16x8*>(&pr[lane * 8]) = hv;
}

// W [K][N] f32 -> WT [N][K] f16  (64x64 tiles via LDS)
__global__ __launch_bounds__(256) void wtrans_kernel(
    const float* __restrict__ W, _Float16* __restrict__ WT, int K, int N) {
  __shared__ float t[64][65];
  const int n0 = blockIdx.x * 64, k0 = blockIdx.y * 64;
  const int tx = threadIdx.x & 63;
  const int ty = threadIdx.x >> 6;
#pragma unroll
  for (int i = 0; i < 16; ++i)
    t[i * 4 + ty][tx] = W[(long)(k0 + i * 4 + ty) * N + n0 + tx];
  __syncthreads();
#pragma unroll
  for (int i = 0; i < 16; ++i) {
    const int r = i * 4 + ty;
    WT[(long)(n0 + r) * K + k0 + tx] = (_Float16)t[tx][r];
  }
}

// pack per-layer qkv biases: bqkv[l][3072]
__global__ __launch_bounds__(256) void packb_kernel(
    const float* __restrict__ bq, const float* __restrict__ bk,
    const float* __restrict__ bv, float* __restrict__ bqkv) {
  const int i = blockIdx.x * 256 + threadIdx.x;
  const int l = i / (3 * DD), j = i % (3 * DD);
  float v;
  if (j < DD) v = bq[l * DD + j];
  else if (j < 2 * DD) v = bk[l * DD + j - DD];
  else v = bv[l * DD + j - 2 * DD];
  bqkv[i] = v;
}

// ---------------------------------------------------------------------------
extern "C" void kernel_launch(void* const* d_in, const int* in_sizes, int n_in,
                              void* d_out, int out_size, void* d_ws,
                              size_t ws_size, hipStream_t stream) {
  const int* ids = (const int*)d_in[0];
  const int* amask = (const int*)d_in[1];
  const int* curp = (const int*)d_in[2];
  const float* tok = (const float*)d_in[3];
  const float* pose = (const float*)d_in[4];
  const float* ln1s = (const float*)d_in[5];
  const float* ln1b = (const float*)d_in[6];
  const float* Wq = (const float*)d_in[7];
  const float* bq = (const float*)d_in[8];
  const float* Wk = (const float*)d_in[9];
  const float* bk = (const float*)d_in[10];
  const float* Wv = (const float*)d_in[11];
  const float* bv = (const float*)d_in[12];
  const float* Wo = (const float*)d_in[13];
  const float* bo = (const float*)d_in[14];
  const float* ln2s = (const float*)d_in[15];
  const float* ln2b = (const float*)d_in[16];
  const float* W1 = (const float*)d_in[17];
  const float* b1 = (const float*)d_in[18];
  const float* W2 = (const float*)d_in[19];
  const float* b2 = (const float*)d_in[20];
  const float* lnfs = (const float*)d_in[21];
  const float* lnfb = (const float*)d_in[22];
  const float* Wout = (const float*)d_in[23];
  const float* bout = (const float*)d_in[24];

  const long MSZ = (long)BB * SS * DD;  // 4M elements
  char* wsp = (char*)d_ws;
  float* h = (float*)wsp;                              // 16MB f32
  _Float16* x = (_Float16*)(wsp + 16u * 1024 * 1024);  // 8MB
  _Float16* q = x + MSZ;    // 8MB  (q, k, vT contiguous: qkv scatter target)
  _Float16* kb = q + MSZ;   // 8MB
  _Float16* vt = kb + MSZ;  // 8MB  [B*H][HD][S]
  _Float16* big = vt + MSZ; // 32MB (scores/probs, MLP mid)
  _Float16* wqkvT = big + (long)BB * HH * SS * SS;  // 6MB [3072][1024]
  _Float16* woT = wqkvT + 3L * DD * DD;             // 2MB
  _Float16* w1T = woT + (long)DD * DD;              // 8MB
  _Float16* w2T = w1T + (long)DD * FFF;             // 8MB
  float* bqkv = (float*)(w2T + (long)FFF * DD);     // 72KB
  _Float16* parts = (_Float16*)(bqkv + LL * 3 * DD);  // 32MB (4x f16 partials)

  const int M = BB * SS;  // 4096
  dim3 blk(256);
  dim3 blk5(512);

  embed_kernel<<<M, blk, 0, stream>>>(ids, curp, tok, pose, h);
  packb_kernel<<<(LL * 3 * DD) / 256, blk, 0, stream>>>(bq, bk, bv, bqkv);

  const dim3 gQKV(3 * DD / 256, M / 256, 1);    // (12,16)
  const dim3 gS(SS / 256, SS / 256, BB * HH);   // (2,2,64)
  const dim3 gV(HDD / 64, SS / 128, BB * HH);   // (2,4,64) gemm2
  const dim3 gF1(FFF / 256, M / 256, 1);        // (16,16)
  const dim3 gKS(DD / 256, M / 256, 4);         // (4,16,4) split-K N=1024
  const dim3 gWt(DD / 64, DD / 64);
  const dim3 gW1t(FFF / 64, DD / 64);
  const dim3 gW2t(DD / 64, FFF / 64);
  const long pzs = (long)M * DD;  // partial stride

  for (int l = 0; l < LL; ++l) {
    wtrans_kernel<<<gWt, blk, 0, stream>>>(Wq + (long)l * DD * DD, wqkvT, DD, DD);
    wtrans_kernel<<<gWt, blk, 0, stream>>>(Wk + (long)l * DD * DD,
                                           wqkvT + (long)DD * DD, DD, DD);
    wtrans_kernel<<<gWt, blk, 0, stream>>>(Wv + (long)l * DD * DD,
                                           wqkvT + 2L * DD * DD, DD, DD);
    wtrans_kernel<<<gWt, blk, 0, stream>>>(Wo + (long)l * DD * DD, woT, DD, DD);
    wtrans_kernel<<<gW1t, blk, 0, stream>>>(W1 + (long)l * DD * FFF, w1T, DD, FFF);
    wtrans_kernel<<<gW2t, blk, 0, stream>>>(W2 + (long)l * FFF * DD, w2T, FFF, DD);

    ln_kernel<<<M, blk, 0, stream>>>(h, ln1s + l * DD, ln1b + l * DD, x);
    // QKV: [4096,3072,1024]
    gemm4_kernel<<<gQKV, blk5, 0, stream>>>(x, wqkvT, bqkv + l * 3 * DD, q,
                                            nullptr, M, 3 * DD, DD, DD, 0, 0,
                                            0, 1);
    // scores: z=64 of [512,512,128]
    gemm4_kernel<<<gS, blk5, 0, stream>>>(q, kb, nullptr, big, amask, SS, SS,
                                          HDD, HDD, (long)SS * HDD,
                                          (long)SS * HDD, (long)SS * SS, 2);
    softmax_kernel<<<(BB * HH * SS) / 4, blk, 0, stream>>>(big);
    // PV: gemm2, z=64 of [512,128,512]
    gemm2_kernel<<<gV, blk, 0, stream>>>(big, vt, x, SS, HDD, SS,
                                         (long)SS * SS, (long)SS * HDD, 0);
    // Wo: split-K4 [4096,1024,1024] -> partials, then reduce(+h residual)
    gemm4_kernel<<<gKS, blk5, 0, stream>>>(x, woT, nullptr, parts, nullptr, M,
                                           DD, DD / 4, DD, DD / 4, DD / 4, pzs,
                                           6);
    reduce4_kernel<<<M, blk, 0, stream>>>(parts, h, bo + l * DD, h, pzs);
    ln_kernel<<<M, blk, 0, stream>>>(h, ln2s + l * DD, ln2b + l * DD, x);
    // MLP up + GELU: [4096,4096,1024]
    gemm4_kernel<<<gF1, blk5, 0, stream>>>(x, w1T, b1 + l * FFF, big, nullptr,
                                           M, FFF, DD, DD, 0, 0, 0, 5);
    // MLP down: split-K4 [4096,1024,4096] -> partials, reduce(+h residual)
    gemm4_kernel<<<gKS, blk5, 0, stream>>>(big, w2T, nullptr, parts, nullptr,
                                           M, DD, FFF / 4, FFF, FFF / 4,
                                           FFF / 4, pzs, 6);
    reduce4_kernel<<<M, blk, 0, stream>>>(parts, h, b2 + l * DD, h, pzs);
  }
  ln_kernel<<<M, blk, 0, stream>>>(h, lnfs, lnfb, x);
  wtrans_kernel<<<gWt, blk, 0, stream>>>(Wout, wqkvT, DD, DD);
  // final: split-K4 [4096,1024,1024] -> partials, reduce(bias only) -> d_out
  gemm4_kernel<<<gKS, blk5, 0, stream>>>(x, wqkvT, nullptr, parts, nullptr, M,
                                         DD, DD / 4, DD, DD / 4, DD / 4, pzs,
                                         6);
  reduce4_kernel<<<M, blk, 0, stream>>>(parts, nullptr, bout, (float*)d_out,
                                        pzs);
}

// Round 7
// 1879.257 us; speedup vs baseline: 1.2181x; 1.2181x over previous
//
#include <hip/hip_runtime.h>
#include <hip/hip_bf16.h>
#include <math.h>

#define BB 8
#define SS 512
#define DD 1024
#define LL 6
#define HH 8
#define HDD 128
#define FFF 4096
#define EPSF 1e-5f
#define SCALEF 0.08838834764831845f  // 1/sqrt(128)

typedef __attribute__((ext_vector_type(8))) _Float16 f16x8;
typedef __attribute__((ext_vector_type(4))) _Float16 f16x4;
typedef __attribute__((ext_vector_type(4))) float f32x4;

__device__ __forceinline__ void gload16(const void* g, void* l) {
  __builtin_amdgcn_global_load_lds(
      (const __attribute__((address_space(1))) void*)g,
      (__attribute__((address_space(3))) void*)l, 16, 0, 0);
}

// ===========================================================================
// gemmk: exact m97 structure. 128x128 tile, BK=32, 4 waves (2x2, 64x64 each),
// SINGLE 16KB LDS buffer, per K-step: {sync; stage 4xgload16; sync;
// 8x ds_read_b128; 16 MFMA}. Swizzle ^((R>>1)&3)<<4 both-sides (R5: verified
// 0 bank conflicts). 3 blocks/CU (VGPR-capped) provide inter-block overlap
// that hides the barrier drain (m97/m114 mechanism, 874 TF measured).
// A [M,K] f16 rows stride Kstr; B [N,K] f16 rows stride Kstr; loop K = Kdim.
// emode: 1 fused-qkv scatter (+bias, V transposed) | 2 scores(scale+mask) |
//        3 pv-scatter | 5 gelu+bias f16 | 6 f16 split-K partial
// ===========================================================================
__global__ __launch_bounds__(256, 3) void gemmk_kernel(
    const _Float16* __restrict__ Ag, const _Float16* __restrict__ Bg,
    const float* __restrict__ bias, void* __restrict__ outp,
    const int* __restrict__ amask, int Ndim, int Kdim, int Kstr,
    long zsA, long zsB, long zsOut, int emode) {
  __shared__ _Float16 lA[4096];  // 8KB: 128 rows x 32 halves (64B rows)
  __shared__ _Float16 lB[4096];
  const int tid = threadIdx.x;
  const int lane = tid & 63;
  const int wid = tid >> 6;
  const int z = blockIdx.z;
  const int m0 = blockIdx.y * 128;
  const int n0 = blockIdx.x * 128;
  const long K2 = (long)Kstr * 2;
  const _Float16* Az = Ag + (long)z * zsA + (long)m0 * Kstr;
  const _Float16* Bz = Bg + (long)z * zsB + (long)n0 * Kstr;

  const int wm = (wid >> 1) * 64;
  const int wn = (wid & 1) * 64;
  const int r16 = lane & 15;
  const int kq = lane >> 4;  // 16B slot 0..3 within 64B row

  // staging: wave w covers rows w*32..w*32+31; 2 loads each for A and B
  const char* As[2];
  const char* Bs[2];
  int ld[2];
#pragma unroll
  for (int i = 0; i < 2; ++i) {
    const int r = wid * 32 + i * 16 + (lane >> 2);
    const int sc = ((lane & 3) << 4) ^ (((r >> 1) & 3) << 4);
    As[i] = (const char*)Az + (long)r * K2 + sc;
    Bs[i] = (const char*)Bz + (long)r * K2 + sc;
    ld[i] = (wid * 128 + i * 64 + lane) * 16;  // linear LDS dest
  }
  // ds_read byte addrs (constant over steps)
  int adA[4], adB[4];
#pragma unroll
  for (int mi = 0; mi < 4; ++mi) {
    const int R = wm + mi * 16 + r16;
    adA[mi] = R * 64 + ((kq ^ ((R >> 1) & 3)) << 4);
  }
#pragma unroll
  for (int ni = 0; ni < 4; ++ni) {
    const int R = wn + ni * 16 + r16;
    adB[ni] = R * 64 + ((kq ^ ((R >> 1) & 3)) << 4);
  }

  f32x4 acc[4][4];
#pragma unroll
  for (int mi = 0; mi < 4; ++mi)
#pragma unroll
    for (int ni = 0; ni < 4; ++ni) acc[mi][ni] = (f32x4){0.f, 0.f, 0.f, 0.f};

  const int nt = Kdim >> 5;
  for (int t = 0; t < nt; ++t) {
    const int kb = t << 6;  // 64B per K-step
    __syncthreads();
#pragma unroll
    for (int i = 0; i < 2; ++i) {
      gload16(As[i] + kb, (char*)lA + ld[i]);
      gload16(Bs[i] + kb, (char*)lB + ld[i]);
    }
    __syncthreads();
    f16x8 af[4], bf[4];
#pragma unroll
    for (int mi = 0; mi < 4; ++mi)
      af[mi] = *(const f16x8*)((const char*)lA + adA[mi]);
#pragma unroll
    for (int ni = 0; ni < 4; ++ni)
      bf[ni] = *(const f16x8*)((const char*)lB + adB[ni]);
#pragma unroll
    for (int mi = 0; mi < 4; ++mi)
#pragma unroll
      for (int ni = 0; ni < 4; ++ni)
        acc[mi][ni] = __builtin_amdgcn_mfma_f32_16x16x32_f16(
            af[mi], bf[ni], acc[mi][ni], 0, 0, 0);
  }

  _Float16* outH = (_Float16*)outp + (long)z * zsOut;
  const int rj = (lane >> 4) << 2;
  const long MSZq = (long)BB * SS * DD;
#pragma unroll
  for (int mi = 0; mi < 4; ++mi) {
#pragma unroll
    for (int ni = 0; ni < 4; ++ni) {
      const int col = n0 + wn + ni * 16 + r16;
#pragma unroll
      for (int j = 0; j < 4; ++j) {
        const int row = m0 + wm + mi * 16 + rj + j;
        float vv = acc[mi][ni][j];
        if (emode == 1) {  // fused qkv scatter; V written transposed
          vv += bias[col];
          int wsel = col >> 10, c = col & 1023;
          int b_ = row >> 9, s_ = row & 511;
          int hh = c >> 7, hd_ = c & 127;
          if (wsel < 2) {
            outH[wsel * MSZq + (((long)(b_ * HH + hh)) * SS + s_) * HDD + hd_] =
                (_Float16)vv;
          } else {  // V -> [B*H][HD][S]
            outH[2 * MSZq + (((long)(b_ * HH + hh)) * HDD + hd_) * SS + s_] =
                (_Float16)vv;
          }
        } else if (emode == 2) {  // scores: scale + key-pad mask
          int b_ = z >> 3;
          vv = (amask[b_ * SS + col] == 0) ? -10000.0f : vv * SCALEF;
          outH[(long)row * Ndim + col] = (_Float16)vv;
        } else if (emode == 3) {  // pv scatter -> x [B,S,D] f16
          int b_ = z >> 3, hh = z & 7;
          outH[((long)(b_ * SS + row)) * DD + hh * HDD + col] = (_Float16)vv;
        } else if (emode == 5) {  // exact GELU(bias+acc), f16
          vv += bias[col];
          vv = 0.5f * vv * (1.0f + erff(vv * 0.70710678118654752f));
          outH[(long)row * Ndim + col] = (_Float16)vv;
        } else {  // 6: f16 split-K partial
          outH[(long)row * Ndim + col] = (_Float16)vv;
        }
      }
    }
  }
}

// ===========================================================================
// reduce_ln: out_h[row] = (res?res:0) + bias + sum_{p<npart} parts[p][row]
// then (if lg) x = LN(out_h; lg,lb) as f16. One block per row (1024 cols).
// ===========================================================================
__global__ __launch_bounds__(256) void reduce_ln_kernel(
    const _Float16* __restrict__ parts, int npart,
    const float* __restrict__ res, const float* __restrict__ bias,
    const float* __restrict__ lg, const float* __restrict__ lb,
    float* __restrict__ hout, _Float16* __restrict__ xout, long pzs) {
  const int row = blockIdx.x;
  const int c = threadIdx.x << 2;
  const long base = (long)row * DD + c;
  float4 a = *reinterpret_cast<const float4*>(&bias[c]);
  if (res) {
    const float4 r = *reinterpret_cast<const float4*>(&res[base]);
    a.x += r.x; a.y += r.y; a.z += r.z; a.w += r.w;
  }
  for (int p = 0; p < npart; ++p) {
    const f16x4 hpv = *reinterpret_cast<const f16x4*>(&parts[p * pzs + base]);
    a.x += (float)hpv[0]; a.y += (float)hpv[1];
    a.z += (float)hpv[2]; a.w += (float)hpv[3];
  }
  *reinterpret_cast<float4*>(&hout[base]) = a;
  if (!lg) return;
  float s = a.x + a.y + a.z + a.w;
  float ss = a.x * a.x + a.y * a.y + a.z * a.z + a.w * a.w;
#pragma unroll
  for (int off = 32; off; off >>= 1) {
    s += __shfl_down(s, off);
    ss += __shfl_down(ss, off);
  }
  __shared__ float red[8];
  const int wid = threadIdx.x >> 6, lane = threadIdx.x & 63;
  if (lane == 0) { red[wid] = s; red[4 + wid] = ss; }
  __syncthreads();
  if (threadIdx.x == 0) {
    s = red[0] + red[1] + red[2] + red[3];
    ss = red[4] + red[5] + red[6] + red[7];
    float mean = s * (1.0f / DD);
    float var = ss * (1.0f / DD) - mean * mean;
    red[0] = mean;
    red[1] = rsqrtf(var + EPSF);
  }
  __syncthreads();
  const float mean = red[0], rstd = red[1];
  const float4 gv = *reinterpret_cast<const float4*>(&lg[c]);
  const float4 bv = *reinterpret_cast<const float4*>(&lb[c]);
  f16x4 o;
  o[0] = (_Float16)((a.x - mean) * rstd * gv.x + bv.x);
  o[1] = (_Float16)((a.y - mean) * rstd * gv.y + bv.y);
  o[2] = (_Float16)((a.z - mean) * rstd * gv.z + bv.z);
  o[3] = (_Float16)((a.w - mean) * rstd * gv.w + bv.w);
  *reinterpret_cast<f16x4*>(&xout[base]) = o;
}

// embed + layer-0 ln1 fused
__global__ __launch_bounds__(256) void embed_ln_kernel(
    const int* __restrict__ ids, const int* __restrict__ curpos,
    const float* __restrict__ tok, const float* __restrict__ pos,
    const float* __restrict__ lg, const float* __restrict__ lb,
    float* __restrict__ h, _Float16* __restrict__ x) {
  const int rs = blockIdx.x;
  const int s_ = rs & (SS - 1);
  const int t = ids[rs];
  const int p = curpos[0] + s_;
  const int c = threadIdx.x << 2;
  const float4 tv = *reinterpret_cast<const float4*>(&tok[(long)t * DD + c]);
  const float4 pv = *reinterpret_cast<const float4*>(&pos[(long)p * DD + c]);
  float4 a = {tv.x + pv.x, tv.y + pv.y, tv.z + pv.z, tv.w + pv.w};
  *reinterpret_cast<float4*>(&h[(long)rs * DD + c]) = a;
  float s = a.x + a.y + a.z + a.w;
  float ss = a.x * a.x + a.y * a.y + a.z * a.z + a.w * a.w;
#pragma unroll
  for (int off = 32; off; off >>= 1) {
    s += __shfl_down(s, off);
    ss += __shfl_down(ss, off);
  }
  __shared__ float red[8];
  const int wid = threadIdx.x >> 6, lane = threadIdx.x & 63;
  if (lane == 0) { red[wid] = s; red[4 + wid] = ss; }
  __syncthreads();
  if (threadIdx.x == 0) {
    s = red[0] + red[1] + red[2] + red[3];
    ss = red[4] + red[5] + red[6] + red[7];
    float mean = s * (1.0f / DD);
    float var = ss * (1.0f / DD) - mean * mean;
    red[0] = mean;
    red[1] = rsqrtf(var + EPSF);
  }
  __syncthreads();
  const float mean = red[0], rstd = red[1];
  const float4 gv = *reinterpret_cast<const float4*>(&lg[c]);
  const float4 bv = *reinterpret_cast<const float4*>(&lb[c]);
  f16x4 o;
  o[0] = (_Float16)((a.x - mean) * rstd * gv.x + bv.x);
  o[1] = (_Float16)((a.y - mean) * rstd * gv.y + bv.y);
  o[2] = (_Float16)((a.z - mean) * rstd * gv.z + bv.z);
  o[3] = (_Float16)((a.w - mean) * rstd * gv.w + bv.w);
  *reinterpret_cast<f16x4*>(&x[(long)rs * DD + c]) = o;
}

// wave-per-row softmax over 512 f16 cols, in place
__global__ __launch_bounds__(256) void softmax_kernel(_Float16* __restrict__ p) {
  const long row = (long)blockIdx.x * 4 + (threadIdx.x >> 6);
  const int lane = threadIdx.x & 63;
  _Float16* pr = p + row * SS;
  f16x8 hv = *reinterpret_cast<const f16x8*>(&pr[lane * 8]);
  float v[8];
#pragma unroll
  for (int j = 0; j < 8; ++j) v[j] = (float)hv[j];
  float m = v[0];
#pragma unroll
  for (int j = 1; j < 8; ++j) m = fmaxf(m, v[j]);
#pragma unroll
  for (int off = 1; off < 64; off <<= 1) m = fmaxf(m, __shfl_xor(m, off));
  float sum = 0.f;
#pragma unroll
  for (int j = 0; j < 8; ++j) {
    v[j] = expf(v[j] - m);
    sum += v[j];
  }
#pragma unroll
  for (int off = 1; off < 64; off <<= 1) sum += __shfl_xor(sum, off);
  const float inv = 1.0f / sum;
#pragma unroll
  for (int j = 0; j < 8; ++j) hv[j] = (_Float16)(v[j] * inv);
  *reinterpret_cast<f16x8*>(&pr[lane * 8]) = hv;
}

// W [K][N] f32 -> WT [N][K] f16  (64x64 tiles via LDS)
__global__ __launch_bounds__(256) void wtrans_kernel(
    const float* __restrict__ W, _Float16* __restrict__ WT, int K, int N) {
  __shared__ float t[64][65];
  const int n0 = blockIdx.x * 64, k0 = blockIdx.y * 64;
  const int tx = threadIdx.x & 63;
  const int ty = threadIdx.x >> 6;
#pragma unroll
  for (int i = 0; i < 16; ++i)
    t[i * 4 + ty][tx] = W[(long)(k0 + i * 4 + ty) * N + n0 + tx];
  __syncthreads();
#pragma unroll
  for (int i = 0; i < 16; ++i) {
    const int r = i * 4 + ty;
    WT[(long)(n0 + r) * K + k0 + tx] = (_Float16)t[tx][r];
  }
}

// pack per-layer qkv biases: bqkv[l][3072]
__global__ __launch_bounds__(256) void packb_kernel(
    const float* __restrict__ bq, const float* __restrict__ bk,
    const float* __restrict__ bv, float* __restrict__ bqkv) {
  const int i = blockIdx.x * 256 + threadIdx.x;
  const int l = i / (3 * DD), j = i % (3 * DD);
  float v;
  if (j < DD) v = bq[l * DD + j];
  else if (j < 2 * DD) v = bk[l * DD + j - DD];
  else v = bv[l * DD + j - 2 * DD];
  bqkv[i] = v;
}

// ---------------------------------------------------------------------------
extern "C" void kernel_launch(void* const* d_in, const int* in_sizes, int n_in,
                              void* d_out, int out_size, void* d_ws,
                              size_t ws_size, hipStream_t stream) {
  const int* ids = (const int*)d_in[0];
  const int* amask = (const int*)d_in[1];
  const int* curp = (const int*)d_in[2];
  const float* tok = (const float*)d_in[3];
  const float* pose = (const float*)d_in[4];
  const float* ln1s = (const float*)d_in[5];
  const float* ln1b = (const float*)d_in[6];
  const float* Wq = (const float*)d_in[7];
  const float* bq = (const float*)d_in[8];
  const float* Wk = (const float*)d_in[9];
  const float* bk = (const float*)d_in[10];
  const float* Wv = (const float*)d_in[11];
  const float* bv = (const float*)d_in[12];
  const float* Wo = (const float*)d_in[13];
  const float* bo = (const float*)d_in[14];
  const float* ln2s = (const float*)d_in[15];
  const float* ln2b = (const float*)d_in[16];
  const float* W1 = (const float*)d_in[17];
  const float* b1 = (const float*)d_in[18];
  const float* W2 = (const float*)d_in[19];
  const float* b2 = (const float*)d_in[20];
  const float* lnfs = (const float*)d_in[21];
  const float* lnfb = (const float*)d_in[22];
  const float* Wout = (const float*)d_in[23];
  const float* bout = (const float*)d_in[24];

  const long MSZ = (long)BB * SS * DD;  // 4M elements
  char* wsp = (char*)d_ws;
  float* h = (float*)wsp;                              // 16MB f32
  _Float16* x = (_Float16*)(wsp + 16u * 1024 * 1024);  // 8MB
  _Float16* q = x + MSZ;    // 8MB (q, k, vT contiguous: qkv scatter target)
  _Float16* kb = q + MSZ;   // 8MB
  _Float16* vt = kb + MSZ;  // 8MB [B*H][HD][S]
  _Float16* big = vt + MSZ; // 32MB (scores/probs, MLP mid)
  _Float16* wqkvT = big + (long)BB * HH * SS * SS;  // 6MB [3072][1024]
  _Float16* woT = wqkvT + 3L * DD * DD;             // 2MB
  _Float16* w1T = woT + (long)DD * DD;              // 8MB
  _Float16* w2T = w1T + (long)DD * FFF;             // 8MB
  float* bqkv = (float*)(w2T + (long)FFF * DD);     // 72KB
  _Float16* parts = (_Float16*)(bqkv + LL * 3 * DD);  // 32MB (4 f16 partials)

  const int M = BB * SS;  // 4096
  dim3 blk(256);
  const long pzs = (long)M * DD;

  embed_ln_kernel<<<M, blk, 0, stream>>>(ids, curp, tok, pose, ln1s, ln1b, h, x);
  packb_kernel<<<(LL * 3 * DD) / 256, blk, 0, stream>>>(bq, bk, bv, bqkv);

  const dim3 gQKV(3 * DD / 128, M / 128, 1);    // (24,32)   768 blocks
  const dim3 gS(SS / 128, SS / 128, BB * HH);   // (4,4,64)  1024
  const dim3 gV(1, SS / 128, BB * HH);          // (1,4,64)  256
  const dim3 gF1(FFF / 128, M / 128, 1);        // (32,32)   1024
  const dim3 gK2(DD / 128, M / 128, 2);         // (8,32,2)  512  split-K2
  const dim3 gK4(DD / 128, M / 128, 4);         // (8,32,4)  1024 split-K4
  const dim3 gWt(DD / 64, DD / 64);
  const dim3 gW1t(FFF / 64, DD / 64);
  const dim3 gW2t(DD / 64, FFF / 64);

  for (int l = 0; l < LL; ++l) {
    wtrans_kernel<<<gWt, blk, 0, stream>>>(Wq + (long)l * DD * DD, wqkvT, DD, DD);
    wtrans_kernel<<<gWt, blk, 0, stream>>>(Wk + (long)l * DD * DD,
                                           wqkvT + (long)DD * DD, DD, DD);
    wtrans_kernel<<<gWt, blk, 0, stream>>>(Wv + (long)l * DD * DD,
                                           wqkvT + 2L * DD * DD, DD, DD);
    wtrans_kernel<<<gWt, blk, 0, stream>>>(Wo + (long)l * DD * DD, woT, DD, DD);
    wtrans_kernel<<<gW1t, blk, 0, stream>>>(W1 + (long)l * DD * FFF, w1T, DD, FFF);
    wtrans_kernel<<<gW2t, blk, 0, stream>>>(W2 + (long)l * FFF * DD, w2T, FFF, DD);

    // QKV: [4096,3072] K=1024
    gemmk_kernel<<<gQKV, blk, 0, stream>>>(x, wqkvT, bqkv + l * 3 * DD, q,
                                           nullptr, 3 * DD, DD, DD, 0, 0, 0, 1);
    // scores: z=64 of [512,512] K=128
    gemmk_kernel<<<gS, blk, 0, stream>>>(q, kb, nullptr, big, amask, SS, HDD,
                                         HDD, (long)SS * HDD, (long)SS * HDD,
                                         (long)SS * SS, 2);
    softmax_kernel<<<(BB * HH * SS) / 4, blk, 0, stream>>>(big);
    // PV: z=64 of [512,128] K=512
    gemmk_kernel<<<gV, blk, 0, stream>>>(big, vt, nullptr, x, nullptr, HDD, SS,
                                         SS, (long)SS * SS, (long)SS * HDD, 0,
                                         3);
    // Wo: split-K2 -> partials; reduce + residual + ln2 -> h, x
    gemmk_kernel<<<gK2, blk, 0, stream>>>(x, woT, nullptr, parts, nullptr, DD,
                                          DD / 2, DD, DD / 2, DD / 2, pzs, 6);
    reduce_ln_kernel<<<M, blk, 0, stream>>>(parts, 2, h, bo + l * DD,
                                            ln2s + l * DD, ln2b + l * DD, h, x,
                                            pzs);
    // MLP up + GELU: [4096,4096] K=1024
    gemmk_kernel<<<gF1, blk, 0, stream>>>(x, w1T, b1 + l * FFF, big, nullptr,
                                          FFF, DD, DD, 0, 0, 0, 5);
    // MLP down: split-K4 -> partials; reduce + residual + next-ln -> h, x
    gemmk_kernel<<<gK4, blk, 0, stream>>>(big, w2T, nullptr, parts, nullptr,
                                          DD, FFF / 4, FFF, FFF / 4, FFF / 4,
                                          pzs, 6);
    const float* ng = (l < LL - 1) ? (ln1s + (l + 1) * DD) : lnfs;
    const float* nb = (l < LL - 1) ? (ln1b + (l + 1) * DD) : lnfb;
    reduce_ln_kernel<<<M, blk, 0, stream>>>(parts, 4, h, b2 + l * DD, ng, nb,
                                            h, x, pzs);
  }
  // final: x @ Wout + bout -> d_out (split-K2, reduce without LN)
  wtrans_kernel<<<gWt, blk, 0, stream>>>(Wout, woT, DD, DD);
  gemmk_kernel<<<gK2, blk, 0, stream>>>(x, woT, nullptr, parts, nullptr, DD,
                                        DD / 2, DD, DD / 2, DD / 2, pzs, 6);
  reduce_ln_kernel<<<M, blk, 0, stream>>>(parts, 2, nullptr, bout, nullptr,
                                          nullptr, (float*)d_out, nullptr, pzs);
}

// Round 8
// 1637.972 us; speedup vs baseline: 1.3975x; 1.1473x over previous
//
#include <hip/hip_runtime.h>
#include <hip/hip_bf16.h>
#include <math.h>

#define BB 8
#define SS 512
#define DD 1024
#define LL 6
#define HH 8
#define HDD 128
#define FFF 4096
#define EPSF 1e-5f
#define SCALEF 0.08838834764831845f  // 1/sqrt(128)

typedef __attribute__((ext_vector_type(8))) _Float16 f16x8;
typedef __attribute__((ext_vector_type(4))) _Float16 f16x4;
typedef __attribute__((ext_vector_type(4))) float f32x4;

__device__ __forceinline__ void gload16(const void* g, void* l) {
  __builtin_amdgcn_global_load_lds(
      (const __attribute__((address_space(1))) void*)g,
      (__attribute__((address_space(3))) void*)l, 16, 0, 0);
}

// ===========================================================================
// gemmk: m97-exact. 128x128 tile, BK=64, 4 waves (2x2, 64x64), single 32KB
// LDS buffer, per K-step: {sync; 8x gload16; sync; 16x ds_read_b128;
// 32 MFMA}. Swizzle ^((r&7)<<4) on 128B rows, both-sides (R2: measured 0
// bank conflicts). 3 blocks/CU via __launch_bounds__(256,3) -> inter-block
// overlap hides the barrier drain (m97/m114 mechanism).
// A [M,K] f16 rows stride Kstr; B [N,K] f16 rows stride Kstr; loop K = Kdim.
// emode: 1 fused-qkv scatter (+bias, V transposed) | 2 scores(scale+mask) |
//        5 gelu+bias f16 | 6 f16 split-K partial
// ===========================================================================
__global__ __launch_bounds__(256, 3) void gemmk_kernel(
    const _Float16* __restrict__ Ag, const _Float16* __restrict__ Bg,
    const float* __restrict__ bias, void* __restrict__ outp,
    const int* __restrict__ amask, int Ndim, int Kdim, int Kstr,
    long zsA, long zsB, long zsOut, int emode) {
  __shared__ _Float16 lA[8192];  // 16KB: 128 rows x 64 halves (128B rows)
  __shared__ _Float16 lB[8192];
  const int tid = threadIdx.x;
  const int lane = tid & 63;
  const int wid = tid >> 6;
  const int z = blockIdx.z;
  const int m0 = blockIdx.y * 128;
  const int n0 = blockIdx.x * 128;
  const long K2 = (long)Kstr * 2;
  const _Float16* Az = Ag + (long)z * zsA + (long)m0 * Kstr;
  const _Float16* Bz = Bg + (long)z * zsB + (long)n0 * Kstr;

  const int wm = (wid >> 1) * 64;
  const int wn = (wid & 1) * 64;
  const int r16 = lane & 15;
  const int kq = lane >> 4;  // 16B slot 0..3

  // staging: 4 chunks; thread i-chunk covers row (tid+i*256)>>3, 16B col
  const char* As[4];
  const char* Bs[4];
  int ldd[4];
#pragma unroll
  for (int i = 0; i < 4; ++i) {
    const int idx = tid + i * 256;
    const int r = idx >> 3;
    const int sc = ((idx & 7) << 4) ^ ((r & 7) << 4);
    As[i] = (const char*)Az + (long)r * K2 + sc;
    Bs[i] = (const char*)Bz + (long)r * K2 + sc;
    ldd[i] = idx * 16;
  }
  // ds_read byte addrs (constant over steps), per kk add kk*64 under XOR
  int adA[4], adB[4];
#pragma unroll
  for (int mi = 0; mi < 4; ++mi) {
    const int R = wm + mi * 16 + r16;
    adA[mi] = R * 128 + ((kq * 16) ^ ((R & 7) << 4));
  }
#pragma unroll
  for (int ni = 0; ni < 4; ++ni) {
    const int R = wn + ni * 16 + r16;
    adB[ni] = R * 128 + ((kq * 16) ^ ((R & 7) << 4));
  }

  f32x4 acc[4][4];
#pragma unroll
  for (int mi = 0; mi < 4; ++mi)
#pragma unroll
    for (int ni = 0; ni < 4; ++ni) acc[mi][ni] = (f32x4){0.f, 0.f, 0.f, 0.f};

  const int nt = Kdim >> 6;
  for (int t = 0; t < nt; ++t) {
    const int kb = t << 7;  // 128B per K-step
    __syncthreads();
#pragma unroll
    for (int i = 0; i < 4; ++i) {
      gload16(As[i] + kb, (char*)lA + ldd[i]);
      gload16(Bs[i] + kb, (char*)lB + ldd[i]);
    }
    __syncthreads();
#pragma unroll
    for (int kk = 0; kk < 2; ++kk) {
      // note: kk*64 has bit6 set; XOR masks span bits 4-6, applied to the
      // full 7-bit col in BOTH staging and read -> consistent bijection.
      f16x8 af[4], bf[4];
#pragma unroll
      for (int mi = 0; mi < 4; ++mi) {
        const int R = wm + mi * 16 + r16;
        af[mi] = *(const f16x8*)((const char*)lA + R * 128 +
                                 ((kk * 64 + kq * 16) ^ ((R & 7) << 4)));
      }
#pragma unroll
      for (int ni = 0; ni < 4; ++ni) {
        const int R = wn + ni * 16 + r16;
        bf[ni] = *(const f16x8*)((const char*)lB + R * 128 +
                                 ((kk * 64 + kq * 16) ^ ((R & 7) << 4)));
      }
#pragma unroll
      for (int mi = 0; mi < 4; ++mi)
#pragma unroll
        for (int ni = 0; ni < 4; ++ni)
          acc[mi][ni] = __builtin_amdgcn_mfma_f32_16x16x32_f16(
              af[mi], bf[ni], acc[mi][ni], 0, 0, 0);
    }
  }

  _Float16* outH = (_Float16*)outp + (long)z * zsOut;
  const int rj = (lane >> 4) << 2;
  const long MSZq = (long)BB * SS * DD;
#pragma unroll
  for (int mi = 0; mi < 4; ++mi) {
#pragma unroll
    for (int ni = 0; ni < 4; ++ni) {
      const int col = n0 + wn + ni * 16 + r16;
#pragma unroll
      for (int j = 0; j < 4; ++j) {
        const int row = m0 + wm + mi * 16 + rj + j;
        float vv = acc[mi][ni][j];
        if (emode == 1) {  // fused qkv scatter; V written transposed
          vv += bias[col];
          int wsel = col >> 10, c = col & 1023;
          int b_ = row >> 9, s_ = row & 511;
          int hh = c >> 7, hd_ = c & 127;
          if (wsel < 2) {
            outH[wsel * MSZq + (((long)(b_ * HH + hh)) * SS + s_) * HDD + hd_] =
                (_Float16)vv;
          } else {  // V -> [B*H][HD][S]
            outH[2 * MSZq + (((long)(b_ * HH + hh)) * HDD + hd_) * SS + s_] =
                (_Float16)vv;
          }
        } else if (emode == 2) {  // scores: scale + key-pad mask
          int b_ = z >> 3;
          vv = (amask[b_ * SS + col] == 0) ? -10000.0f : vv * SCALEF;
          outH[(long)row * Ndim + col] = (_Float16)vv;
        } else if (emode == 5) {  // exact GELU(bias+acc), f16
          vv += bias[col];
          vv = 0.5f * vv * (1.0f + erff(vv * 0.70710678118654752f));
          outH[(long)row * Ndim + col] = (_Float16)vv;
        } else {  // 6: f16 split-K partial
          outH[(long)row * Ndim + col] = (_Float16)vv;
        }
      }
    }
  }
}

// ===========================================================================
// flashpv: fused online-softmax + PV. One block per (128-q-tile, b*h).
// Reads raw scaled+masked scores S [BH][S][S] f16 (L2/L3-resident) directly
// into PV A-fragments; per-row stats entirely in registers (rows r16-mapped,
// stats shared across kq lanes via shfl_xor 16/32; moved to C-layout rows
// rj+j via shfl). V read as B-fragments from vt [BH][HD][S]. No LDS.
// ===========================================================================
__global__ __launch_bounds__(256) void flashpv_kernel(
    const _Float16* __restrict__ Sg, const _Float16* __restrict__ Vt,
    _Float16* __restrict__ xout) {
  const int tid = threadIdx.x;
  const int lane = tid & 63;
  const int wid = tid >> 6;
  const int bh = blockIdx.y;
  const int q0 = blockIdx.x * 128;
  const int wm = (wid >> 1) * 64;
  const int wn = (wid & 1) * 64;
  const int r16 = lane & 15;
  const int kq = lane >> 4;
  const int rj = kq << 2;
  const _Float16* Sb = Sg + (long)bh * SS * SS + (long)q0 * SS;
  const _Float16* Vb = Vt + (long)bh * HDD * SS;

  f32x4 acc[4][4];
#pragma unroll
  for (int mi = 0; mi < 4; ++mi)
#pragma unroll
    for (int ni = 0; ni < 4; ++ni) acc[mi][ni] = (f32x4){0.f, 0.f, 0.f, 0.f};
  float m[4], l[4];
#pragma unroll
  for (int mi = 0; mi < 4; ++mi) {
    m[mi] = -INFINITY;
    l[mi] = 0.f;
  }

  for (int kt = 0; kt < 4; ++kt) {
    const int kvb = kt * 128;
    f16x8 pa[4][4];
    float rf[4];
#pragma unroll
    for (int mi = 0; mi < 4; ++mi) {
      f16x8 sf[4];
#pragma unroll
      for (int ks = 0; ks < 4; ++ks)
        sf[ks] = *(const f16x8*)(Sb + (long)(wm + mi * 16 + r16) * SS + kvb +
                                 ks * 32 + kq * 8);
      float tm = -INFINITY;
#pragma unroll
      for (int ks = 0; ks < 4; ++ks)
#pragma unroll
        for (int e = 0; e < 8; ++e) tm = fmaxf(tm, (float)sf[ks][e]);
      tm = fmaxf(tm, __shfl_xor(tm, 16));
      tm = fmaxf(tm, __shfl_xor(tm, 32));
      const float mn = fmaxf(m[mi], tm);
      rf[mi] = __expf(m[mi] - mn);
      m[mi] = mn;
      float rs = 0.f;
#pragma unroll
      for (int ks = 0; ks < 4; ++ks) {
        f16x8 p;
#pragma unroll
        for (int e = 0; e < 8; ++e) {
          const float pv = __expf((float)sf[ks][e] - mn);
          rs += pv;
          p[e] = (_Float16)pv;
        }
        pa[mi][ks] = p;
      }
      rs += __shfl_xor(rs, 16);
      rs += __shfl_xor(rs, 32);
      l[mi] = l[mi] * rf[mi] + rs;
    }
    // rescale existing accumulator rows by exp(m_old - m_new)
#pragma unroll
    for (int mi = 0; mi < 4; ++mi)
#pragma unroll
      for (int j = 0; j < 4; ++j) {
        const float f = __shfl(rf[mi], (lane & 48) | (rj + j));
#pragma unroll
        for (int ni = 0; ni < 4; ++ni) acc[mi][ni][j] *= f;
      }
    // PV MFMAs
#pragma unroll
    for (int ks = 0; ks < 4; ++ks) {
      f16x8 bf[4];
#pragma unroll
      for (int ni = 0; ni < 4; ++ni)
        bf[ni] = *(const f16x8*)(Vb + (long)(wn + ni * 16 + r16) * SS + kvb +
                                 ks * 32 + kq * 8);
#pragma unroll
      for (int mi = 0; mi < 4; ++mi)
#pragma unroll
        for (int ni = 0; ni < 4; ++ni)
          acc[mi][ni] = __builtin_amdgcn_mfma_f32_16x16x32_f16(
              pa[mi][ks], bf[ni], acc[mi][ni], 0, 0, 0);
    }
  }

  float linv[4];
#pragma unroll
  for (int mi = 0; mi < 4; ++mi) linv[mi] = 1.0f / l[mi];
  const int b_ = bh >> 3, hh = bh & 7;
#pragma unroll
  for (int mi = 0; mi < 4; ++mi)
#pragma unroll
    for (int j = 0; j < 4; ++j) {
      const float f = __shfl(linv[mi], (lane & 48) | (rj + j));
      const int row = q0 + wm + mi * 16 + rj + j;
#pragma unroll
      for (int ni = 0; ni < 4; ++ni) {
        const int col = wn + ni * 16 + r16;
        xout[((long)(b_ * SS + row)) * DD + hh * HDD + col] =
            (_Float16)(acc[mi][ni][j] * f);
      }
    }
}

// ===========================================================================
// reduce_ln: h[row] = (res?res:0) + bias + sum parts; optional LN -> x (f16)
// ===========================================================================
__global__ __launch_bounds__(256) void reduce_ln_kernel(
    const _Float16* __restrict__ parts, int npart,
    const float* __restrict__ res, const float* __restrict__ bias,
    const float* __restrict__ lg, const float* __restrict__ lb,
    float* __restrict__ hout, _Float16* __restrict__ xout, long pzs) {
  const int row = blockIdx.x;
  const int c = threadIdx.x << 2;
  const long base = (long)row * DD + c;
  float4 a = *reinterpret_cast<const float4*>(&bias[c]);
  if (res) {
    const float4 r = *reinterpret_cast<const float4*>(&res[base]);
    a.x += r.x; a.y += r.y; a.z += r.z; a.w += r.w;
  }
  for (int p = 0; p < npart; ++p) {
    const f16x4 hpv = *reinterpret_cast<const f16x4*>(&parts[p * pzs + base]);
    a.x += (float)hpv[0]; a.y += (float)hpv[1];
    a.z += (float)hpv[2]; a.w += (float)hpv[3];
  }
  *reinterpret_cast<float4*>(&hout[base]) = a;
  if (!lg) return;
  float s = a.x + a.y + a.z + a.w;
  float ss = a.x * a.x + a.y * a.y + a.z * a.z + a.w * a.w;
#pragma unroll
  for (int off = 32; off; off >>= 1) {
    s += __shfl_down(s, off);
    ss += __shfl_down(ss, off);
  }
  __shared__ float red[8];
  const int wid = threadIdx.x >> 6, lane = threadIdx.x & 63;
  if (lane == 0) { red[wid] = s; red[4 + wid] = ss; }
  __syncthreads();
  if (threadIdx.x == 0) {
    s = red[0] + red[1] + red[2] + red[3];
    ss = red[4] + red[5] + red[6] + red[7];
    float mean = s * (1.0f / DD);
    float var = ss * (1.0f / DD) - mean * mean;
    red[0] = mean;
    red[1] = rsqrtf(var + EPSF);
  }
  __syncthreads();
  const float mean = red[0], rstd = red[1];
  const float4 gv = *reinterpret_cast<const float4*>(&lg[c]);
  const float4 bv = *reinterpret_cast<const float4*>(&lb[c]);
  f16x4 o;
  o[0] = (_Float16)((a.x - mean) * rstd * gv.x + bv.x);
  o[1] = (_Float16)((a.y - mean) * rstd * gv.y + bv.y);
  o[2] = (_Float16)((a.z - mean) * rstd * gv.z + bv.z);
  o[3] = (_Float16)((a.w - mean) * rstd * gv.w + bv.w);
  *reinterpret_cast<f16x4*>(&xout[base]) = o;
}

// embed + layer-0 ln1 fused
__global__ __launch_bounds__(256) void embed_ln_kernel(
    const int* __restrict__ ids, const int* __restrict__ curpos,
    const float* __restrict__ tok, const float* __restrict__ pos,
    const float* __restrict__ lg, const float* __restrict__ lb,
    float* __restrict__ h, _Float16* __restrict__ x) {
  const int rs = blockIdx.x;
  const int s_ = rs & (SS - 1);
  const int t = ids[rs];
  const int p = curpos[0] + s_;
  const int c = threadIdx.x << 2;
  const float4 tv = *reinterpret_cast<const float4*>(&tok[(long)t * DD + c]);
  const float4 pv = *reinterpret_cast<const float4*>(&pos[(long)p * DD + c]);
  float4 a = {tv.x + pv.x, tv.y + pv.y, tv.z + pv.z, tv.w + pv.w};
  *reinterpret_cast<float4*>(&h[(long)rs * DD + c]) = a;
  float s = a.x + a.y + a.z + a.w;
  float ss = a.x * a.x + a.y * a.y + a.z * a.z + a.w * a.w;
#pragma unroll
  for (int off = 32; off; off >>= 1) {
    s += __shfl_down(s, off);
    ss += __shfl_down(ss, off);
  }
  __shared__ float red[8];
  const int wid = threadIdx.x >> 6, lane = threadIdx.x & 63;
  if (lane == 0) { red[wid] = s; red[4 + wid] = ss; }
  __syncthreads();
  if (threadIdx.x == 0) {
    s = red[0] + red[1] + red[2] + red[3];
    ss = red[4] + red[5] + red[6] + red[7];
    float mean = s * (1.0f / DD);
    float var = ss * (1.0f / DD) - mean * mean;
    red[0] = mean;
    red[1] = rsqrtf(var + EPSF);
  }
  __syncthreads();
  const float mean = red[0], rstd = red[1];
  const float4 gv = *reinterpret_cast<const float4*>(&lg[c]);
  const float4 bv = *reinterpret_cast<const float4*>(&lb[c]);
  f16x4 o;
  o[0] = (_Float16)((a.x - mean) * rstd * gv.x + bv.x);
  o[1] = (_Float16)((a.y - mean) * rstd * gv.y + bv.y);
  o[2] = (_Float16)((a.z - mean) * rstd * gv.z + bv.z);
  o[3] = (_Float16)((a.w - mean) * rstd * gv.w + bv.w);
  *reinterpret_cast<f16x4*>(&x[(long)rs * DD + c]) = o;
}

// batched DxD transpose: z=0..2 -> wqkvT slabs, z=3 -> woT
__global__ __launch_bounds__(256) void wtrans4_kernel(
    const float* __restrict__ Wq, const float* __restrict__ Wk,
    const float* __restrict__ Wv, const float* __restrict__ Wo,
    _Float16* __restrict__ qkvT, _Float16* __restrict__ woT) {
  __shared__ float t[64][65];
  const int zz = blockIdx.z;
  const float* W = (zz == 0) ? Wq : (zz == 1) ? Wk : (zz == 2) ? Wv : Wo;
  _Float16* WT = (zz < 3) ? (qkvT + (long)zz * DD * DD) : woT;
  const int n0 = blockIdx.x * 64, k0 = blockIdx.y * 64;
  const int tx = threadIdx.x & 63;
  const int ty = threadIdx.x >> 6;
#pragma unroll
  for (int i = 0; i < 16; ++i)
    t[i * 4 + ty][tx] = W[(long)(k0 + i * 4 + ty) * DD + n0 + tx];
  __syncthreads();
#pragma unroll
  for (int i = 0; i < 16; ++i) {
    const int r = i * 4 + ty;
    WT[(long)(n0 + r) * DD + k0 + tx] = (_Float16)t[tx][r];
  }
}

// W [K][N] f32 -> WT [N][K] f16
__global__ __launch_bounds__(256) void wtrans_kernel(
    const float* __restrict__ W, _Float16* __restrict__ WT, int K, int N) {
  __shared__ float t[64][65];
  const int n0 = blockIdx.x * 64, k0 = blockIdx.y * 64;
  const int tx = threadIdx.x & 63;
  const int ty = threadIdx.x >> 6;
#pragma unroll
  for (int i = 0; i < 16; ++i)
    t[i * 4 + ty][tx] = W[(long)(k0 + i * 4 + ty) * N + n0 + tx];
  __syncthreads();
#pragma unroll
  for (int i = 0; i < 16; ++i) {
    const int r = i * 4 + ty;
    WT[(long)(n0 + r) * K + k0 + tx] = (_Float16)t[tx][r];
  }
}

// pack per-layer qkv biases: bqkv[l][3072]
__global__ __launch_bounds__(256) void packb_kernel(
    const float* __restrict__ bq, const float* __restrict__ bk,
    const float* __restrict__ bv, float* __restrict__ bqkv) {
  const int i = blockIdx.x * 256 + threadIdx.x;
  const int l = i / (3 * DD), j = i % (3 * DD);
  float v;
  if (j < DD) v = bq[l * DD + j];
  else if (j < 2 * DD) v = bk[l * DD + j - DD];
  else v = bv[l * DD + j - 2 * DD];
  bqkv[i] = v;
}

// ---------------------------------------------------------------------------
extern "C" void kernel_launch(void* const* d_in, const int* in_sizes, int n_in,
                              void* d_out, int out_size, void* d_ws,
                              size_t ws_size, hipStream_t stream) {
  const int* ids = (const int*)d_in[0];
  const int* amask = (const int*)d_in[1];
  const int* curp = (const int*)d_in[2];
  const float* tok = (const float*)d_in[3];
  const float* pose = (const float*)d_in[4];
  const float* ln1s = (const float*)d_in[5];
  const float* ln1b = (const float*)d_in[6];
  const float* Wq = (const float*)d_in[7];
  const float* bq = (const float*)d_in[8];
  const float* Wk = (const float*)d_in[9];
  const float* bk = (const float*)d_in[10];
  const float* Wv = (const float*)d_in[11];
  const float* bv = (const float*)d_in[12];
  const float* Wo = (const float*)d_in[13];
  const float* bo = (const float*)d_in[14];
  const float* ln2s = (const float*)d_in[15];
  const float* ln2b = (const float*)d_in[16];
  const float* W1 = (const float*)d_in[17];
  const float* b1 = (const float*)d_in[18];
  const float* W2 = (const float*)d_in[19];
  const float* b2 = (const float*)d_in[20];
  const float* lnfs = (const float*)d_in[21];
  const float* lnfb = (const float*)d_in[22];
  const float* Wout = (const float*)d_in[23];
  const float* bout = (const float*)d_in[24];

  const long MSZ = (long)BB * SS * DD;  // 4M elements
  char* wsp = (char*)d_ws;
  float* h = (float*)wsp;                              // 16MB f32
  _Float16* x = (_Float16*)(wsp + 16u * 1024 * 1024);  // 8MB
  _Float16* q = x + MSZ;    // 8MB (q, k, vT contiguous: qkv scatter target)
  _Float16* kb = q + MSZ;   // 8MB
  _Float16* vt = kb + MSZ;  // 8MB [B*H][HD][S]
  _Float16* big = vt + MSZ; // 32MB (scores, MLP mid)
  _Float16* wqkvT = big + (long)BB * HH * SS * SS;  // 6MB [3072][1024]
  _Float16* woT = wqkvT + 3L * DD * DD;             // 2MB
  _Float16* w1T = woT + (long)DD * DD;              // 8MB
  _Float16* w2T = w1T + (long)DD * FFF;             // 8MB
  float* bqkv = (float*)(w2T + (long)FFF * DD);     // 72KB
  _Float16* parts = (_Float16*)(bqkv + LL * 3 * DD);  // 32MB (4 f16 partials)

  const int M = BB * SS;  // 4096
  dim3 blk(256);
  const long pzs = (long)M * DD;

  embed_ln_kernel<<<M, blk, 0, stream>>>(ids, curp, tok, pose, ln1s, ln1b, h, x);
  packb_kernel<<<(LL * 3 * DD) / 256, blk, 0, stream>>>(bq, bk, bv, bqkv);

  const dim3 gQKV(3 * DD / 128, M / 128, 1);    // (24,32)   768 blocks
  const dim3 gS(SS / 128, SS / 128, BB * HH);   // (4,4,64)  1024
  const dim3 gPV(SS / 128, BB * HH);            // (4,64)    256
  const dim3 gF1(FFF / 128, M / 128, 1);        // (32,32)   1024
  const dim3 gK2(DD / 128, M / 128, 2);         // (8,32,2)  512  split-K2
  const dim3 gK4(DD / 128, M / 128, 4);         // (8,32,4)  1024 split-K4
  const dim3 gWt4(DD / 64, DD / 64, 4);
  const dim3 gWt(DD / 64, DD / 64);
  const dim3 gW1t(FFF / 64, DD / 64);
  const dim3 gW2t(DD / 64, FFF / 64);

  for (int l = 0; l < LL; ++l) {
    const long lo = (long)l * DD * DD;
    wtrans4_kernel<<<gWt4, blk, 0, stream>>>(Wq + lo, Wk + lo, Wv + lo, Wo + lo,
                                             wqkvT, woT);
    wtrans_kernel<<<gW1t, blk, 0, stream>>>(W1 + (long)l * DD * FFF, w1T, DD, FFF);
    wtrans_kernel<<<gW2t, blk, 0, stream>>>(W2 + (long)l * FFF * DD, w2T, FFF, DD);

    // QKV: [4096,3072] K=1024
    gemmk_kernel<<<gQKV, blk, 0, stream>>>(x, wqkvT, bqkv + l * 3 * DD, q,
                                           nullptr, 3 * DD, DD, DD, 0, 0, 0, 1);
    // scores: z=64 of [512,512] K=128 (scale+mask applied in epilogue)
    gemmk_kernel<<<gS, blk, 0, stream>>>(q, kb, nullptr, big, amask, SS, HDD,
                                         HDD, (long)SS * HDD, (long)SS * HDD,
                                         (long)SS * SS, 2);
    // fused online-softmax + PV -> x
    flashpv_kernel<<<gPV, blk, 0, stream>>>(big, vt, x);
    // Wo: split-K2 -> partials; reduce + residual + ln2 -> h, x
    gemmk_kernel<<<gK2, blk, 0, stream>>>(x, woT, nullptr, parts, nullptr, DD,
                                          DD / 2, DD, DD / 2, DD / 2, pzs, 6);
    reduce_ln_kernel<<<M, blk, 0, stream>>>(parts, 2, h, bo + l * DD,
                                            ln2s + l * DD, ln2b + l * DD, h, x,
                                            pzs);
    // MLP up + GELU: [4096,4096] K=1024
    gemmk_kernel<<<gF1, blk, 0, stream>>>(x, w1T, b1 + l * FFF, big, nullptr,
                                          FFF, DD, DD, 0, 0, 0, 5);
    // MLP down: split-K4 -> partials; reduce + residual + next-ln -> h, x
    gemmk_kernel<<<gK4, blk, 0, stream>>>(big, w2T, nullptr, parts, nullptr,
                                          DD, FFF / 4, FFF, FFF / 4, FFF / 4,
                                          pzs, 6);
    const float* ng = (l < LL - 1) ? (ln1s + (l + 1) * DD) : lnfs;
    const float* nb = (l < LL - 1) ? (ln1b + (l + 1) * DD) : lnfb;
    reduce_ln_kernel<<<M, blk, 0, stream>>>(parts, 4, h, b2 + l * DD, ng, nb,
                                            h, x, pzs);
  }
  // final: x @ Wout + bout -> d_out (split-K2, reduce without LN)
  wtrans_kernel<<<gWt, blk, 0, stream>>>(Wout, woT, DD, DD);
  gemmk_kernel<<<gK2, blk, 0, stream>>>(x, woT, nullptr, parts, nullptr, DD,
                                        DD / 2, DD, DD / 2, DD / 2, pzs, 6);
  reduce_ln_kernel<<<M, blk, 0, stream>>>(parts, 2, nullptr, bout, nullptr,
                                          nullptr, (float*)d_out, nullptr, pzs);
}

// Round 9
// 1602.750 us; speedup vs baseline: 1.4282x; 1.0220x over previous
//
#include <hip/hip_runtime.h>
#include <hip/hip_bf16.h>
#include <math.h>

#define BB 8
#define SS 512
#define DD 1024
#define LL 6
#define HH 8
#define HDD 128
#define FFF 4096
#define EPSF 1e-5f
#define SCALEF 0.08838834764831845f  // 1/sqrt(128)

typedef __attribute__((ext_vector_type(8))) _Float16 f16x8;
typedef __attribute__((ext_vector_type(4))) _Float16 f16x4;
typedef __attribute__((ext_vector_type(4))) float f32x4;

__device__ __forceinline__ void gload16(const void* g, void* l) {
  __builtin_amdgcn_global_load_lds(
      (const __attribute__((address_space(1))) void*)g,
      (__attribute__((address_space(3))) void*)l, 16, 0, 0);
}

// ===========================================================================
// gemmk: m97-exact (unchanged from R8, proven). 128x128 tile, BK=64, 4 waves,
// single 32KB LDS buffer, swizzle ^((r&7)<<4), 3 blocks/CU.
// emode: 1 fused-qkv scatter (+bias, V transposed) | 5 gelu+bias f16 |
//        6 f16 split-K partial
// ===========================================================================
__global__ __launch_bounds__(256, 3) void gemmk_kernel(
    const _Float16* __restrict__ Ag, const _Float16* __restrict__ Bg,
    const float* __restrict__ bias, void* __restrict__ outp,
    int Ndim, int Kdim, int Kstr, long zsA, long zsB, long zsOut, int emode) {
  __shared__ _Float16 lA[8192];  // 16KB: 128 rows x 64 halves (128B rows)
  __shared__ _Float16 lB[8192];
  const int tid = threadIdx.x;
  const int lane = tid & 63;
  const int wid = tid >> 6;
  const int z = blockIdx.z;
  const int m0 = blockIdx.y * 128;
  const int n0 = blockIdx.x * 128;
  const long K2 = (long)Kstr * 2;
  const _Float16* Az = Ag + (long)z * zsA + (long)m0 * Kstr;
  const _Float16* Bz = Bg + (long)z * zsB + (long)n0 * Kstr;

  const int wm = (wid >> 1) * 64;
  const int wn = (wid & 1) * 64;
  const int r16 = lane & 15;
  const int kq = lane >> 4;  // 16B slot 0..3

  const char* As[4];
  const char* Bs[4];
  int ldd[4];
#pragma unroll
  for (int i = 0; i < 4; ++i) {
    const int idx = tid + i * 256;
    const int r = idx >> 3;
    const int sc = ((idx & 7) << 4) ^ ((r & 7) << 4);
    As[i] = (const char*)Az + (long)r * K2 + sc;
    Bs[i] = (const char*)Bz + (long)r * K2 + sc;
    ldd[i] = idx * 16;
  }

  f32x4 acc[4][4];
#pragma unroll
  for (int mi = 0; mi < 4; ++mi)
#pragma unroll
    for (int ni = 0; ni < 4; ++ni) acc[mi][ni] = (f32x4){0.f, 0.f, 0.f, 0.f};

  const int nt = Kdim >> 6;
  for (int t = 0; t < nt; ++t) {
    const int kb = t << 7;  // 128B per K-step
    __syncthreads();
#pragma unroll
    for (int i = 0; i < 4; ++i) {
      gload16(As[i] + kb, (char*)lA + ldd[i]);
      gload16(Bs[i] + kb, (char*)lB + ldd[i]);
    }
    __syncthreads();
#pragma unroll
    for (int kk = 0; kk < 2; ++kk) {
      f16x8 af[4], bf[4];
#pragma unroll
      for (int mi = 0; mi < 4; ++mi) {
        const int R = wm + mi * 16 + r16;
        af[mi] = *(const f16x8*)((const char*)lA + R * 128 +
                                 ((kk * 64 + kq * 16) ^ ((R & 7) << 4)));
      }
#pragma unroll
      for (int ni = 0; ni < 4; ++ni) {
        const int R = wn + ni * 16 + r16;
        bf[ni] = *(const f16x8*)((const char*)lB + R * 128 +
                                 ((kk * 64 + kq * 16) ^ ((R & 7) << 4)));
      }
#pragma unroll
      for (int mi = 0; mi < 4; ++mi)
#pragma unroll
        for (int ni = 0; ni < 4; ++ni)
          acc[mi][ni] = __builtin_amdgcn_mfma_f32_16x16x32_f16(
              af[mi], bf[ni], acc[mi][ni], 0, 0, 0);
    }
  }

  _Float16* outH = (_Float16*)outp + (long)z * zsOut;
  const int rj = (lane >> 4) << 2;
  const long MSZq = (long)BB * SS * DD;
#pragma unroll
  for (int mi = 0; mi < 4; ++mi) {
#pragma unroll
    for (int ni = 0; ni < 4; ++ni) {
      const int col = n0 + wn + ni * 16 + r16;
#pragma unroll
      for (int j = 0; j < 4; ++j) {
        const int row = m0 + wm + mi * 16 + rj + j;
        float vv = acc[mi][ni][j];
        if (emode == 1) {  // fused qkv scatter; V written transposed
          vv += bias[col];
          int wsel = col >> 10, c = col & 1023;
          int b_ = row >> 9, s_ = row & 511;
          int hh = c >> 7, hd_ = c & 127;
          if (wsel < 2) {
            outH[wsel * MSZq + (((long)(b_ * HH + hh)) * SS + s_) * HDD + hd_] =
                (_Float16)vv;
          } else {  // V -> [B*H][HD][S]
            outH[2 * MSZq + (((long)(b_ * HH + hh)) * HDD + hd_) * SS + s_] =
                (_Float16)vv;
          }
        } else if (emode == 5) {  // exact GELU(bias+acc), f16
          vv += bias[col];
          vv = 0.5f * vv * (1.0f + erff(vv * 0.70710678118654752f));
          outH[(long)row * Ndim + col] = (_Float16)vv;
        } else {  // 6: f16 split-K partial
          outH[(long)row * Ndim + col] = (_Float16)vv;
        }
      }
    }
  }
}

// ===========================================================================
// flash: fused QK^T + online softmax + PV. Block = (128-q-tile, bh), 4 waves,
// wave owns a 32-q strip x all 512 s x all 128 hd. Q/K read as MFMA frags
// direct from global. P transposed via per-wave LDS [32][136]. PV computed
// SWAPPED (out^T = mfma(V^T-rows, P-as-B)) so rescale/1-over-l are per-lane
// scalars (col = q); row factors broadcast through a 32-float LDS array.
// ===========================================================================
__global__ __launch_bounds__(256) void flash_kernel(
    const _Float16* __restrict__ Qg, const _Float16* __restrict__ Kg,
    const _Float16* __restrict__ Vt, const int* __restrict__ amask,
    _Float16* __restrict__ xout) {
  __shared__ _Float16 Pl[4][32][136];
  __shared__ float rf_s[4][32];
  const int tid = threadIdx.x;
  const int lane = tid & 63;
  const int w = tid >> 6;
  const int bh = blockIdx.y;
  const int b_ = bh >> 3, hh = bh & 7;
  const int q0 = blockIdx.x * 128 + w * 32;
  const int r16 = lane & 15;
  const int kq = lane >> 4;
  const int rj = kq << 2;
  const _Float16* Qb = Qg + ((long)bh * SS + q0) * HDD;
  const _Float16* Kb = Kg + (long)bh * SS * HDD;
  const _Float16* Vb = Vt + (long)bh * HDD * SS;

  // Q A-frags: rows q0+mi*16+r16, k = kk*32 + kq*8
  f16x8 qa[2][4];
#pragma unroll
  for (int mi = 0; mi < 2; ++mi)
#pragma unroll
    for (int kk = 0; kk < 4; ++kk)
      qa[mi][kk] = *(const f16x8*)(Qb + (long)(mi * 16 + r16) * HDD + kk * 32 +
                                   kq * 8);

  f32x4 acc[8][2];  // out^T: [hd 8x16][q 2x16]
#pragma unroll
  for (int mi = 0; mi < 8; ++mi)
#pragma unroll
    for (int ni = 0; ni < 2; ++ni) acc[mi][ni] = (f32x4){0.f, 0.f, 0.f, 0.f};
  float mrun[2][4], lrun[2][4];
#pragma unroll
  for (int mi = 0; mi < 2; ++mi)
#pragma unroll
    for (int j = 0; j < 4; ++j) {
      mrun[mi][j] = -INFINITY;
      lrun[mi][j] = 0.f;
    }

  for (int kt = 0; kt < 4; ++kt) {
    __syncthreads();  // protect P/rf_s reuse across iterations
    const int s0 = kt * 128;
    int am[8];
#pragma unroll
    for (int ni = 0; ni < 8; ++ni)
      am[ni] = amask[b_ * SS + s0 + ni * 16 + r16];

    // QK^T: sc[q 2x16][s 8x16]
    f32x4 sc[2][8];
#pragma unroll
    for (int mi = 0; mi < 2; ++mi)
#pragma unroll
      for (int ni = 0; ni < 8; ++ni) sc[mi][ni] = (f32x4){0.f, 0.f, 0.f, 0.f};
#pragma unroll
    for (int ni = 0; ni < 8; ++ni) {
      f16x8 kf[4];
#pragma unroll
      for (int kk = 0; kk < 4; ++kk)
        kf[kk] = *(const f16x8*)(Kb + (long)(s0 + ni * 16 + r16) * HDD +
                                 kk * 32 + kq * 8);
#pragma unroll
      for (int mi = 0; mi < 2; ++mi)
#pragma unroll
        for (int kk = 0; kk < 4; ++kk)
          sc[mi][ni] = __builtin_amdgcn_mfma_f32_16x16x32_f16(
              qa[mi][kk], kf[kk], sc[mi][ni], 0, 0, 0);
    }
    // scale + mask (col s = ni*16 + r16 -> am[ni], lane-local)
#pragma unroll
    for (int mi = 0; mi < 2; ++mi)
#pragma unroll
      for (int ni = 0; ni < 8; ++ni)
#pragma unroll
        for (int j = 0; j < 4; ++j)
          sc[mi][ni][j] = am[ni] ? sc[mi][ni][j] * SCALEF : -10000.0f;

    // online softmax per row (q = mi*16 + rj + j); cols spread over r16 lanes
    float rf[2][4];
#pragma unroll
    for (int mi = 0; mi < 2; ++mi)
#pragma unroll
      for (int j = 0; j < 4; ++j) {
        float rm = -INFINITY;
#pragma unroll
        for (int ni = 0; ni < 8; ++ni) rm = fmaxf(rm, sc[mi][ni][j]);
#pragma unroll
        for (int off = 1; off < 16; off <<= 1)
          rm = fmaxf(rm, __shfl_xor(rm, off));
        const float mn = fmaxf(mrun[mi][j], rm);
        const float rfv = __expf(mrun[mi][j] - mn);
        mrun[mi][j] = mn;
        float rs = 0.f;
#pragma unroll
        for (int ni = 0; ni < 8; ++ni) {
          const float p = __expf(sc[mi][ni][j] - mn);
          sc[mi][ni][j] = p;
          rs += p;
        }
#pragma unroll
        for (int off = 1; off < 16; off <<= 1) rs += __shfl_xor(rs, off);
        lrun[mi][j] = lrun[mi][j] * rfv + rs;
        rf[mi][j] = rfv;
      }
    if (r16 == 0) {
#pragma unroll
      for (int mi = 0; mi < 2; ++mi)
#pragma unroll
        for (int j = 0; j < 4; ++j) rf_s[w][mi * 16 + rj + j] = rf[mi][j];
    }
#pragma unroll
    for (int mi = 0; mi < 2; ++mi)
#pragma unroll
      for (int ni = 0; ni < 8; ++ni)
#pragma unroll
        for (int j = 0; j < 4; ++j)
          Pl[w][mi * 16 + rj + j][ni * 16 + r16] = (_Float16)sc[mi][ni][j];
    __syncthreads();

    // rescale acc (col q = ni2*16 + r16 -> per-lane scalar)
    float rfq[2];
    rfq[0] = rf_s[w][r16];
    rfq[1] = rf_s[w][16 + r16];
#pragma unroll
    for (int mi2 = 0; mi2 < 8; ++mi2)
#pragma unroll
      for (int ni2 = 0; ni2 < 2; ++ni2)
#pragma unroll
        for (int j = 0; j < 4; ++j) acc[mi2][ni2][j] *= rfq[ni2];

    // PV swapped: A = V^T rows (hd, k=s), B = P rows (q, k=s)
    f16x8 pb[2][4];
#pragma unroll
    for (int ni2 = 0; ni2 < 2; ++ni2)
#pragma unroll
      for (int kk = 0; kk < 4; ++kk)
        pb[ni2][kk] =
            *(const f16x8*)(&Pl[w][ni2 * 16 + r16][kk * 32 + kq * 8]);
#pragma unroll
    for (int mi2 = 0; mi2 < 8; ++mi2) {
      f16x8 va[4];
#pragma unroll
      for (int kk = 0; kk < 4; ++kk)
        va[kk] = *(const f16x8*)(Vb + (long)(mi2 * 16 + r16) * SS + s0 +
                                 kk * 32 + kq * 8);
#pragma unroll
      for (int ni2 = 0; ni2 < 2; ++ni2)
#pragma unroll
        for (int kk = 0; kk < 4; ++kk)
          acc[mi2][ni2] = __builtin_amdgcn_mfma_f32_16x16x32_f16(
              va[kk], pb[ni2][kk], acc[mi2][ni2], 0, 0, 0);
    }
  }

  // epilogue: divide by l, store out^T element (row=hd, col=q)
  __syncthreads();
  if (r16 == 0) {
#pragma unroll
    for (int mi = 0; mi < 2; ++mi)
#pragma unroll
      for (int j = 0; j < 4; ++j)
        rf_s[w][mi * 16 + rj + j] = 1.0f / lrun[mi][j];
  }
  __syncthreads();
  float lq[2];
  lq[0] = rf_s[w][r16];
  lq[1] = rf_s[w][16 + r16];
#pragma unroll
  for (int mi2 = 0; mi2 < 8; ++mi2)
#pragma unroll
    for (int ni2 = 0; ni2 < 2; ++ni2) {
      f16x4 o;
#pragma unroll
      for (int j = 0; j < 4; ++j) o[j] = (_Float16)(acc[mi2][ni2][j] * lq[ni2]);
      const int qg = q0 + ni2 * 16 + r16;
      *(f16x4*)(&xout[((long)(b_ * SS + qg)) * DD + hh * HDD + mi2 * 16 + rj]) =
          o;
    }
}

// ===========================================================================
// reduce_ln: h[row] = (res?res:0) + bias + sum parts; optional LN -> x (f16)
// ===========================================================================
__global__ __launch_bounds__(256) void reduce_ln_kernel(
    const _Float16* __restrict__ parts, int npart,
    const float* __restrict__ res, const float* __restrict__ bias,
    const float* __restrict__ lg, const float* __restrict__ lb,
    float* __restrict__ hout, _Float16* __restrict__ xout, long pzs) {
  const int row = blockIdx.x;
  const int c = threadIdx.x << 2;
  const long base = (long)row * DD + c;
  float4 a = *reinterpret_cast<const float4*>(&bias[c]);
  if (res) {
    const float4 r = *reinterpret_cast<const float4*>(&res[base]);
    a.x += r.x; a.y += r.y; a.z += r.z; a.w += r.w;
  }
  for (int p = 0; p < npart; ++p) {
    const f16x4 hpv = *reinterpret_cast<const f16x4*>(&parts[p * pzs + base]);
    a.x += (float)hpv[0]; a.y += (float)hpv[1];
    a.z += (float)hpv[2]; a.w += (float)hpv[3];
  }
  *reinterpret_cast<float4*>(&hout[base]) = a;
  if (!lg) return;
  float s = a.x + a.y + a.z + a.w;
  float ss = a.x * a.x + a.y * a.y + a.z * a.z + a.w * a.w;
#pragma unroll
  for (int off = 32; off; off >>= 1) {
    s += __shfl_down(s, off);
    ss += __shfl_down(ss, off);
  }
  __shared__ float red[8];
  const int wid = threadIdx.x >> 6, lane = threadIdx.x & 63;
  if (lane == 0) { red[wid] = s; red[4 + wid] = ss; }
  __syncthreads();
  if (threadIdx.x == 0) {
    s = red[0] + red[1] + red[2] + red[3];
    ss = red[4] + red[5] + red[6] + red[7];
    float mean = s * (1.0f / DD);
    float var = ss * (1.0f / DD) - mean * mean;
    red[0] = mean;
    red[1] = rsqrtf(var + EPSF);
  }
  __syncthreads();
  const float mean = red[0], rstd = red[1];
  const float4 gv = *reinterpret_cast<const float4*>(&lg[c]);
  const float4 bv = *reinterpret_cast<const float4*>(&lb[c]);
  f16x4 o;
  o[0] = (_Float16)((a.x - mean) * rstd * gv.x + bv.x);
  o[1] = (_Float16)((a.y - mean) * rstd * gv.y + bv.y);
  o[2] = (_Float16)((a.z - mean) * rstd * gv.z + bv.z);
  o[3] = (_Float16)((a.w - mean) * rstd * gv.w + bv.w);
  *reinterpret_cast<f16x4*>(&xout[base]) = o;
}

// embed + layer-0 ln1 fused
__global__ __launch_bounds__(256) void embed_ln_kernel(
    const int* __restrict__ ids, const int* __restrict__ curpos,
    const float* __restrict__ tok, const float* __restrict__ pos,
    const float* __restrict__ lg, const float* __restrict__ lb,
    float* __restrict__ h, _Float16* __restrict__ x) {
  const int rs = blockIdx.x;
  const int s_ = rs & (SS - 1);
  const int t = ids[rs];
  const int p = curpos[0] + s_;
  const int c = threadIdx.x << 2;
  const float4 tv = *reinterpret_cast<const float4*>(&tok[(long)t * DD + c]);
  const float4 pv = *reinterpret_cast<const float4*>(&pos[(long)p * DD + c]);
  float4 a = {tv.x + pv.x, tv.y + pv.y, tv.z + pv.z, tv.w + pv.w};
  *reinterpret_cast<float4*>(&h[(long)rs * DD + c]) = a;
  float s = a.x + a.y + a.z + a.w;
  float ss = a.x * a.x + a.y * a.y + a.z * a.z + a.w * a.w;
#pragma unroll
  for (int off = 32; off; off >>= 1) {
    s += __shfl_down(s, off);
    ss += __shfl_down(ss, off);
  }
  __shared__ float red[8];
  const int wid = threadIdx.x >> 6, lane = threadIdx.x & 63;
  if (lane == 0) { red[wid] = s; red[4 + wid] = ss; }
  __syncthreads();
  if (threadIdx.x == 0) {
    s = red[0] + red[1] + red[2] + red[3];
    ss = red[4] + red[5] + red[6] + red[7];
    float mean = s * (1.0f / DD);
    float var = ss * (1.0f / DD) - mean * mean;
    red[0] = mean;
    red[1] = rsqrtf(var + EPSF);
  }
  __syncthreads();
  const float mean = red[0], rstd = red[1];
  const float4 gv = *reinterpret_cast<const float4*>(&lg[c]);
  const float4 bv = *reinterpret_cast<const float4*>(&lb[c]);
  f16x4 o;
  o[0] = (_Float16)((a.x - mean) * rstd * gv.x + bv.x);
  o[1] = (_Float16)((a.y - mean) * rstd * gv.y + bv.y);
  o[2] = (_Float16)((a.z - mean) * rstd * gv.z + bv.z);
  o[3] = (_Float16)((a.w - mean) * rstd * gv.w + bv.w);
  *reinterpret_cast<f16x4*>(&x[(long)rs * DD + c]) = o;
}

// all 6 per-layer weight transposes in one launch (3072 blocks, decode id)
__global__ __launch_bounds__(256) void wtransall_kernel(
    const float* __restrict__ Wq, const float* __restrict__ Wk,
    const float* __restrict__ Wv, const float* __restrict__ Wo,
    const float* __restrict__ W1, const float* __restrict__ W2, int l,
    _Float16* __restrict__ qkvT, _Float16* __restrict__ woT,
    _Float16* __restrict__ w1T, _Float16* __restrict__ w2T) {
  __shared__ float tt[64][65];
  const int id = blockIdx.x;
  const float* src;
  _Float16* dst;
  int K, N, t;
  const long lo = (long)l * DD * DD;
  const long lof = (long)l * DD * FFF;
  if (id < 1024) {
    const int wsel = id >> 8;
    t = id & 255;
    src = (wsel == 0 ? Wq : wsel == 1 ? Wk : wsel == 2 ? Wv : Wo) + lo;
    dst = (wsel < 3) ? (qkvT + (long)wsel * DD * DD) : woT;
    K = DD; N = DD;
  } else if (id < 2048) {
    t = id - 1024; src = W1 + lof; dst = w1T; K = DD; N = FFF;
  } else {
    t = id - 2048; src = W2 + lof; dst = w2T; K = FFF; N = DD;
  }
  const int ntile = N >> 6;
  const int n0 = (t % ntile) << 6;
  const int k0 = (t / ntile) << 6;
  const int tx = threadIdx.x & 63;
  const int ty = threadIdx.x >> 6;
#pragma unroll
  for (int i = 0; i < 16; ++i)
    tt[i * 4 + ty][tx] = src[(long)(k0 + i * 4 + ty) * N + n0 + tx];
  __syncthreads();
#pragma unroll
  for (int i = 0; i < 16; ++i) {
    const int r = i * 4 + ty;
    dst[(long)(n0 + r) * K + k0 + tx] = (_Float16)tt[tx][r];
  }
}

// W [K][N] f32 -> WT [N][K] f16 (final Wout)
__global__ __launch_bounds__(256) void wtrans_kernel(
    const float* __restrict__ W, _Float16* __restrict__ WT, int K, int N) {
  __shared__ float tt[64][65];
  const int n0 = blockIdx.x * 64, k0 = blockIdx.y * 64;
  const int tx = threadIdx.x & 63;
  const int ty = threadIdx.x >> 6;
#pragma unroll
  for (int i = 0; i < 16; ++i)
    tt[i * 4 + ty][tx] = W[(long)(k0 + i * 4 + ty) * N + n0 + tx];
  __syncthreads();
#pragma unroll
  for (int i = 0; i < 16; ++i) {
    const int r = i * 4 + ty;
    WT[(long)(n0 + r) * K + k0 + tx] = (_Float16)tt[tx][r];
  }
}

// pack per-layer qkv biases: bqkv[l][3072]
__global__ __launch_bounds__(256) void packb_kernel(
    const float* __restrict__ bq, const float* __restrict__ bk,
    const float* __restrict__ bv, float* __restrict__ bqkv) {
  const int i = blockIdx.x * 256 + threadIdx.x;
  const int l = i / (3 * DD), j = i % (3 * DD);
  float v;
  if (j < DD) v = bq[l * DD + j];
  else if (j < 2 * DD) v = bk[l * DD + j - DD];
  else v = bv[l * DD + j - 2 * DD];
  bqkv[i] = v;
}

// ---------------------------------------------------------------------------
extern "C" void kernel_launch(void* const* d_in, const int* in_sizes, int n_in,
                              void* d_out, int out_size, void* d_ws,
                              size_t ws_size, hipStream_t stream) {
  const int* ids = (const int*)d_in[0];
  const int* amask = (const int*)d_in[1];
  const int* curp = (const int*)d_in[2];
  const float* tok = (const float*)d_in[3];
  const float* pose = (const float*)d_in[4];
  const float* ln1s = (const float*)d_in[5];
  const float* ln1b = (const float*)d_in[6];
  const float* Wq = (const float*)d_in[7];
  const float* bq = (const float*)d_in[8];
  const float* Wk = (const float*)d_in[9];
  const float* bk = (const float*)d_in[10];
  const float* Wv = (const float*)d_in[11];
  const float* bv = (const float*)d_in[12];
  const float* Wo = (const float*)d_in[13];
  const float* bo = (const float*)d_in[14];
  const float* ln2s = (const float*)d_in[15];
  const float* ln2b = (const float*)d_in[16];
  const float* W1 = (const float*)d_in[17];
  const float* b1 = (const float*)d_in[18];
  const float* W2 = (const float*)d_in[19];
  const float* b2 = (const float*)d_in[20];
  const float* lnfs = (const float*)d_in[21];
  const float* lnfb = (const float*)d_in[22];
  const float* Wout = (const float*)d_in[23];
  const float* bout = (const float*)d_in[24];

  const long MSZ = (long)BB * SS * DD;  // 4M elements
  char* wsp = (char*)d_ws;
  float* h = (float*)wsp;                              // 16MB f32
  _Float16* x = (_Float16*)(wsp + 16u * 1024 * 1024);  // 8MB
  _Float16* q = x + MSZ;    // 8MB (q, k, vT contiguous: qkv scatter target)
  _Float16* kb = q + MSZ;   // 8MB
  _Float16* vt = kb + MSZ;  // 8MB [B*H][HD][S]
  _Float16* big = vt + MSZ; // 32MB (MLP mid)
  _Float16* wqkvT = big + (long)BB * HH * SS * SS;  // 6MB [3072][1024]
  _Float16* woT = wqkvT + 3L * DD * DD;             // 2MB
  _Float16* w1T = woT + (long)DD * DD;              // 8MB
  _Float16* w2T = w1T + (long)DD * FFF;             // 8MB
  float* bqkv = (float*)(w2T + (long)FFF * DD);     // 72KB
  _Float16* parts = (_Float16*)(bqkv + LL * 3 * DD);  // 32MB (4 f16 partials)

  const int M = BB * SS;  // 4096
  dim3 blk(256);
  const long pzs = (long)M * DD;

  embed_ln_kernel<<<M, blk, 0, stream>>>(ids, curp, tok, pose, ln1s, ln1b, h, x);
  packb_kernel<<<(LL * 3 * DD) / 256, blk, 0, stream>>>(bq, bk, bv, bqkv);

  const dim3 gQKV(3 * DD / 128, M / 128, 1);    // (24,32)   768 blocks
  const dim3 gFA(SS / 128, BB * HH);            // (4,64)    256
  const dim3 gF1(FFF / 128, M / 128, 1);        // (32,32)   1024
  const dim3 gK2(DD / 128, M / 128, 2);         // (8,32,2)  512  split-K2
  const dim3 gK4(DD / 128, M / 128, 4);         // (8,32,4)  1024 split-K4
  const dim3 gWt(DD / 64, DD / 64);

  for (int l = 0; l < LL; ++l) {
    wtransall_kernel<<<3072, blk, 0, stream>>>(Wq, Wk, Wv, Wo, W1, W2, l,
                                               wqkvT, woT, w1T, w2T);
    // QKV: [4096,3072] K=1024
    gemmk_kernel<<<gQKV, blk, 0, stream>>>(x, wqkvT, bqkv + l * 3 * DD, q,
                                           3 * DD, DD, DD, 0, 0, 0, 1);
    // fused flash attention -> x [B,S,D] f16
    flash_kernel<<<gFA, blk, 0, stream>>>(q, kb, vt, amask, x);
    // Wo: split-K2 -> partials; reduce + residual + ln2 -> h, x
    gemmk_kernel<<<gK2, blk, 0, stream>>>(x, woT, nullptr, parts, DD, DD / 2,
                                          DD, DD / 2, DD / 2, pzs, 6);
    reduce_ln_kernel<<<M, blk, 0, stream>>>(parts, 2, h, bo + l * DD,
                                            ln2s + l * DD, ln2b + l * DD, h, x,
                                            pzs);
    // MLP up + GELU: [4096,4096] K=1024
    gemmk_kernel<<<gF1, blk, 0, stream>>>(x, w1T, b1 + l * FFF, big, FFF, DD,
                                          DD, 0, 0, 0, 5);
    // MLP down: split-K4 -> partials; reduce + residual + next-ln -> h, x
    gemmk_kernel<<<gK4, blk, 0, stream>>>(big, w2T, nullptr, parts, DD,
                                          FFF / 4, FFF, FFF / 4, FFF / 4, pzs,
                                          6);
    const float* ng = (l < LL - 1) ? (ln1s + (l + 1) * DD) : lnfs;
    const float* nb = (l < LL - 1) ? (ln1b + (l + 1) * DD) : lnfb;
    reduce_ln_kernel<<<M, blk, 0, stream>>>(parts, 4, h, b2 + l * DD, ng, nb,
                                            h, x, pzs);
  }
  // final: x @ Wout + bout -> d_out (split-K2, reduce without LN)
  wtrans_kernel<<<gWt, blk, 0, stream>>>(Wout, woT, DD, DD);
  gemmk_kernel<<<gK2, blk, 0, stream>>>(x, woT, nullptr, parts, DD, DD / 2,
                                        DD, DD / 2, DD / 2, pzs, 6);
  reduce_ln_kernel<<<M, blk, 0, stream>>>(parts, 2, nullptr, bout, nullptr,
                                          nullptr, (float*)d_out, nullptr, pzs);
}